// Round 9
// baseline (144.341 us; speedup 1.0000x reference)
//
#include <hip/hip_runtime.h>

#define EPS_BN 1e-5f
#define MFMA16 __builtin_amdgcn_mfma_f32_16x16x32_bf16

typedef unsigned char uchar;
typedef short short8 __attribute__((ext_vector_type(8)));
typedef float f32x4 __attribute__((ext_vector_type(4)));

__device__ __forceinline__ ushort f2bf(float f) {
    unsigned u = __float_as_uint(f);
    return (ushort)((u + 0x7FFFu + ((u >> 16) & 1u)) >> 16);   // RNE
}
__device__ __forceinline__ float bf2f(ushort h) {
    return __uint_as_float(((unsigned)h) << 16);
}
// async global->LDS, 16B per lane; lds dest = wave-uniform base + lane*16
__device__ __forceinline__ void gload_lds16(const void* g, void* l) {
    __builtin_amdgcn_global_load_lds(
        (const __attribute__((address_space(1))) void*)g,
        (__attribute__((address_space(3))) void*)l, 16, 0, 0);
}

// ---------------------------------------------------------------------------
// x[4,256,256,64] f32, mask[4,256,256] i32 (active==0), w1[3,3,64,128],
// w2[3,3,128,128], out[4,128,128,128] f32.
// Convs as implicit GEMM, M=64px x N=128co blocks (grid 1024), BK=64,
// LDS 48KB dbuf -> 3 blocks/CU (12 waves/CU). K-loop fully unrolled,
// all DMA addresses hoisted to per-thread bases + compile-time offsets.
// LDS chunk swizzle: LDS[row][cd] holds G[row][cd ^ (row&7)] (16B chunks);
// frag read byte = (row*128 + ks*64 + lg*16) ^ ((row&7)<<4).
// MFMA fragment maps (mfma_f32_16x16x32_bf16):
//   A: lane(lr,lg)=lr+16*lg holds A[row=lr][k=lg*8..+8)
//   B: lane holds B[k=lg*8..+8)[col=lr]; weights stored [co][ci] so co=col
//   D: lane holds D[row=lg*4+r][col=lr], r=0..3
// ---------------------------------------------------------------------------

__global__ __launch_bounds__(256) void mask_kernel(const int* __restrict__ mask,
                                                   uchar* __restrict__ m1,
                                                   int* __restrict__ cnt)
{
    int idx = blockIdx.x * 256 + threadIdx.x;   // 65536
    int ow = idx & 127;
    int oh = (idx >> 7) & 127;
    int b  = idx >> 14;
    bool act = false;
    #pragma unroll
    for (int kh = 0; kh < 3; ++kh) {
        int ih = 2*oh - 1 + kh;
        if ((unsigned)ih >= 256u) continue;
        #pragma unroll
        for (int kw = 0; kw < 3; ++kw) {
            int iw = 2*ow - 1 + kw;
            if ((unsigned)iw >= 256u) continue;
            if (mask[(b*256 + ih)*256 + iw] == 0) act = true;
        }
    }
    m1[idx] = act ? 1 : 0;
    unsigned long long bal = __ballot(act);
    if ((threadIdx.x & 63) == 0)
        atomicAdd(cnt, (int)__popcll(bal));
}

// masked input -> bf16: xb[px*64 + ci]
__global__ __launch_bounds__(256) void xcvt_kernel(const float* __restrict__ x,
                                                   const int* __restrict__ mask,
                                                   ushort* __restrict__ xb)
{
    int idx = blockIdx.x * 256 + threadIdx.x;   // 2,097,152 chunks of 8
    int px = idx >> 3;
    int c0 = (idx & 7) * 8;
    short8 o = {0,0,0,0,0,0,0,0};
    if (mask[px] == 0) {
        const float* p = x + (size_t)px * 64 + c0;
        #pragma unroll
        for (int j = 0; j < 8; ++j) o[j] = (short)f2bf(p[j]);
    }
    *(short8*)(xb + (size_t)px * 64 + c0) = o;
}

// weights -> bf16, transposed to [kh*3+kw][co][ci]
__global__ __launch_bounds__(256) void wcvt_kernel(const float* __restrict__ w1,
                                                   const float* __restrict__ w2,
                                                   ushort* __restrict__ w1T,
                                                   ushort* __restrict__ w2T)
{
    int idx = blockIdx.x * 256 + threadIdx.x;   // 221184 total
    if (idx < 73728) {                          // 9*128*64
        int ci = idx & 63;
        int co = (idx >> 6) & 127;
        int s  = idx >> 13;
        w1T[idx] = f2bf(w1[(s*64 + ci)*128 + co]);
    } else if (idx < 221184) {
        int i  = idx - 73728;                   // 9*128*128
        int ci = i & 127;
        int co = (i >> 7) & 127;
        int s  = i >> 14;
        w2T[i] = f2bf(w2[(s*128 + ci)*128 + co]);
    }
}

// conv1: 3x3 s2, 64->128. Block = 64 output px x 128 co, grid 1024.
__global__ __launch_bounds__(256, 3) void conv1_mfma(const ushort* __restrict__ xb,
                                                     const ushort* __restrict__ w1T,
                                                     const ushort* __restrict__ zp,
                                                     const uchar* __restrict__ m1,
                                                     ushort* __restrict__ out1,
                                                     float* __restrict__ stats)
{
    __shared__ ushort At[2][4096];   // 8KB per buf: [64px][64ci] swizzled
    __shared__ ushort Bt[2][8192];   // 16KB per buf: [128co][64ci]

    const int t     = threadIdx.x;
    const int lane  = t & 63;
    const int wv    = t >> 6;
    const int wbase = t & ~63;
    const int blk   = blockIdx.x;    // 1024 = b*256 + oh*2 + half
    const int half  = blk & 1;
    const int oh    = (blk >> 1) & 127;
    const int b     = blk >> 8;

    const int wm = wv >> 1, wn = wv & 1;    // wave: 32px x 64co
    const int lr = lane & 15, lg = lane >> 4;

    // ---- hoisted staging geometry ----
    const int rowA = t >> 3;                 // 0..31 (r=1 adds 32)
    const int cdA  = t & 7;
    const int csA  = cdA ^ (rowA & 7);       // (row+32)&7 == row&7
    const ushort* pA[2][3];
    bool cok[2][3], rok[3];
    #pragma unroll
    for (int r = 0; r < 2; ++r) {
        int pxg = half*64 + rowA + r*32;
        int c0  = 2*pxg - 1;
        #pragma unroll
        for (int kw = 0; kw < 3; ++kw) cok[r][kw] = ((unsigned)(c0 + kw) < 256u);
        #pragma unroll
        for (int kh = 0; kh < 3; ++kh) {
            int ih  = 2*oh + kh - 1;
            int ihc = ih < 0 ? 0 : (ih > 255 ? 255 : ih);
            pA[r][kh] = xb + ((size_t)(b*256 + ihc)*256 + c0)*64 + csA*8;
        }
    }
    #pragma unroll
    for (int kh = 0; kh < 3; ++kh) rok[kh] = ((unsigned)(2*oh + kh - 1) < 256u);
    const ushort* pB[4];
    #pragma unroll
    for (int r = 0; r < 4; ++r) {
        int idx = r*256 + t;
        int co = idx >> 3, bcd = idx & 7, bcs = bcd ^ (co & 7);
        pB[r] = w1T + (size_t)co*64 + bcs*8;
    }

    auto dma = [&](int bf, int s) {      // s compile-time after unroll
        const int kh = s / 3, kw = s % 3;
        #pragma unroll
        for (int r = 0; r < 2; ++r) {
            const ushort* g = (rok[kh] && cok[r][kw]) ? pA[r][kh] + kw*64 : zp;
            gload_lds16(g, &At[bf][(size_t)(r*256 + wbase)*8]);
        }
        #pragma unroll
        for (int r = 0; r < 4; ++r)
            gload_lds16(pB[r] + (size_t)s*8192, &Bt[bf][(size_t)(r*256 + wbase)*8]);
    };

    f32x4 acc[2][4];
    #pragma unroll
    for (int mi = 0; mi < 2; ++mi)
        #pragma unroll
        for (int ni = 0; ni < 4; ++ni)
            acc[mi][ni] = (f32x4){0.f, 0.f, 0.f, 0.f};

    dma(0, 0);
    __syncthreads();
    #pragma unroll
    for (int kt = 0; kt < 9; ++kt) {
        const int cb = kt & 1;
        if (kt < 8) dma(cb ^ 1, kt + 1);
        const char* Ab = (const char*)At[cb];
        const char* Bb = (const char*)Bt[cb];
        #pragma unroll
        for (int ks = 0; ks < 2; ++ks) {
            short8 af[2], bfr[4];
            #pragma unroll
            for (int mi = 0; mi < 2; ++mi) {
                int row = wm*32 + mi*16 + lr;
                af[mi] = *(const short8*)(Ab + ((row*128 + ks*64 + lg*16) ^ ((row & 7) << 4)));
            }
            #pragma unroll
            for (int ni = 0; ni < 4; ++ni) {
                int co = wn*64 + ni*16 + lr;
                bfr[ni] = *(const short8*)(Bb + ((co*128 + ks*64 + lg*16) ^ ((co & 7) << 4)));
            }
            #pragma unroll
            for (int mi = 0; mi < 2; ++mi)
                #pragma unroll
                for (int ni = 0; ni < 4; ++ni)
                    acc[mi][ni] = MFMA16(af[mi], bfr[ni], acc[mi][ni], 0, 0, 0);
        }
        __syncthreads();
    }

    const size_t pixbase = ((size_t)(b*128 + oh))*128 + half*64;
    #pragma unroll
    for (int mi = 0; mi < 2; ++mi) {
        #pragma unroll
        for (int ni = 0; ni < 4; ++ni) {
            int px = wm*32 + mi*16 + lg*4;
            int co = wn*64 + ni*16 + lr;
            #pragma unroll
            for (int r = 0; r < 4; ++r)
                out1[(pixbase + px + r)*128 + co] = f2bf(acc[mi][ni][r]);
        }
    }

    // ---- fused BN1 stats (single barrier round) ----
    float s4[4] = {0.f,0.f,0.f,0.f}, q4[4] = {0.f,0.f,0.f,0.f};
    #pragma unroll
    for (int mi = 0; mi < 2; ++mi) {
        const uchar* mp = m1 + pixbase + wm*32 + mi*16 + lg*4;
        #pragma unroll
        for (int r = 0; r < 4; ++r) {
            float a = mp[r] ? 1.f : 0.f;
            #pragma unroll
            for (int ni = 0; ni < 4; ++ni) {
                float av = a * acc[mi][ni][r];
                s4[ni] += av;
                q4[ni] += av * acc[mi][ni][r];
            }
        }
    }
    float* red = (float*)At;   // 8KB needed <= 16KB avail; K-loop done
    const int rrow = wm*4 + lg;
    #pragma unroll
    for (int ni = 0; ni < 4; ++ni) {
        red[rrow*128 + wn*64 + ni*16 + lr]        = s4[ni];
        red[1024 + rrow*128 + wn*64 + ni*16 + lr] = q4[ni];
    }
    __syncthreads();
    if (t < 128) {
        float v = 0.f, q = 0.f;
        #pragma unroll
        for (int rr = 0; rr < 8; ++rr) { v += red[rr*128 + t]; q += red[1024 + rr*128 + t]; }
        atomicAdd(&stats[t], v);
        atomicAdd(&stats[128 + t], q);
    }
}

// conv2: 3x3 s1, 128->128 on bnrelu'd out1. Block = 64px x 128co, grid 1024.
__global__ __launch_bounds__(256, 3) void conv2_mfma(const ushort* __restrict__ a,
                                                     const ushort* __restrict__ w2T,
                                                     const ushort* __restrict__ zp,
                                                     const uchar* __restrict__ m1,
                                                     float* __restrict__ outraw,
                                                     float* __restrict__ stats)
{
    __shared__ ushort At[2][4096];
    __shared__ ushort Bt[2][8192];

    const int t     = threadIdx.x;
    const int lane  = t & 63;
    const int wv    = t >> 6;
    const int wbase = t & ~63;
    const int blk   = blockIdx.x;    // 1024 = b*256 + oh*2 + half
    const int half  = blk & 1;
    const int oh    = (blk >> 1) & 127;
    const int b     = blk >> 8;

    const int wm = wv >> 1, wn = wv & 1;
    const int lr = lane & 15, lg = lane >> 4;

    const int rowA = t >> 3;
    const int cdA  = t & 7;
    const int csA  = cdA ^ (rowA & 7);
    const ushort* pA[2][3];
    bool cok[2][3], rok[3];
    #pragma unroll
    for (int r = 0; r < 2; ++r) {
        int pxg = half*64 + rowA + r*32;
        int c0  = pxg - 1;
        #pragma unroll
        for (int kw = 0; kw < 3; ++kw) cok[r][kw] = ((unsigned)(c0 + kw) < 128u);
        #pragma unroll
        for (int kh = 0; kh < 3; ++kh) {
            int ih  = oh + kh - 1;
            int ihc = ih < 0 ? 0 : (ih > 127 ? 127 : ih);
            pA[r][kh] = a + ((size_t)(b*128 + ihc)*128 + c0)*128 + csA*8;
        }
    }
    #pragma unroll
    for (int kh = 0; kh < 3; ++kh) rok[kh] = ((unsigned)(oh + kh - 1) < 128u);
    const ushort* pB[4];
    #pragma unroll
    for (int r = 0; r < 4; ++r) {
        int idx = r*256 + t;
        int co = idx >> 3, bcd = idx & 7, bcs = bcd ^ (co & 7);
        pB[r] = w2T + (size_t)co*128 + bcs*8;
    }

    auto dma = [&](int bf, int kt) {    // kt compile-time after unroll
        const int s = kt >> 1, h = kt & 1;
        const int kh = s / 3, kw = s % 3;
        #pragma unroll
        for (int r = 0; r < 2; ++r) {
            const ushort* g = (rok[kh] && cok[r][kw]) ? pA[r][kh] + kw*128 + h*64 : zp;
            gload_lds16(g, &At[bf][(size_t)(r*256 + wbase)*8]);
        }
        #pragma unroll
        for (int r = 0; r < 4; ++r)
            gload_lds16(pB[r] + (size_t)s*16384 + h*64,
                        &Bt[bf][(size_t)(r*256 + wbase)*8]);
    };

    f32x4 acc[2][4];
    #pragma unroll
    for (int mi = 0; mi < 2; ++mi)
        #pragma unroll
        for (int ni = 0; ni < 4; ++ni)
            acc[mi][ni] = (f32x4){0.f, 0.f, 0.f, 0.f};

    dma(0, 0);
    __syncthreads();
    #pragma unroll
    for (int kt = 0; kt < 18; ++kt) {
        const int cb = kt & 1;
        if (kt < 17) dma(cb ^ 1, kt + 1);
        const char* Ab = (const char*)At[cb];
        const char* Bb = (const char*)Bt[cb];
        #pragma unroll
        for (int ks = 0; ks < 2; ++ks) {
            short8 af[2], bfr[4];
            #pragma unroll
            for (int mi = 0; mi < 2; ++mi) {
                int row = wm*32 + mi*16 + lr;
                af[mi] = *(const short8*)(Ab + ((row*128 + ks*64 + lg*16) ^ ((row & 7) << 4)));
            }
            #pragma unroll
            for (int ni = 0; ni < 4; ++ni) {
                int co = wn*64 + ni*16 + lr;
                bfr[ni] = *(const short8*)(Bb + ((co*128 + ks*64 + lg*16) ^ ((co & 7) << 4)));
            }
            #pragma unroll
            for (int mi = 0; mi < 2; ++mi)
                #pragma unroll
                for (int ni = 0; ni < 4; ++ni)
                    acc[mi][ni] = MFMA16(af[mi], bfr[ni], acc[mi][ni], 0, 0, 0);
        }
        __syncthreads();
    }

    const size_t pixbase = ((size_t)(b*128 + oh))*128 + half*64;
    #pragma unroll
    for (int mi = 0; mi < 2; ++mi) {
        #pragma unroll
        for (int ni = 0; ni < 4; ++ni) {
            int px = wm*32 + mi*16 + lg*4;
            int co = wn*64 + ni*16 + lr;
            #pragma unroll
            for (int r = 0; r < 4; ++r)
                outraw[(pixbase + px + r)*128 + co] = acc[mi][ni][r];
        }
    }

    // ---- fused BN2 stats ----
    float s4[4] = {0.f,0.f,0.f,0.f}, q4[4] = {0.f,0.f,0.f,0.f};
    #pragma unroll
    for (int mi = 0; mi < 2; ++mi) {
        const uchar* mp = m1 + pixbase + wm*32 + mi*16 + lg*4;
        #pragma unroll
        for (int r = 0; r < 4; ++r) {
            float av0 = mp[r] ? 1.f : 0.f;
            #pragma unroll
            for (int ni = 0; ni < 4; ++ni) {
                float av = av0 * acc[mi][ni][r];
                s4[ni] += av;
                q4[ni] += av * acc[mi][ni][r];
            }
        }
    }
    float* red = (float*)At;
    const int rrow = wm*4 + lg;
    #pragma unroll
    for (int ni = 0; ni < 4; ++ni) {
        red[rrow*128 + wn*64 + ni*16 + lr]        = s4[ni];
        red[1024 + rrow*128 + wn*64 + ni*16 + lr] = q4[ni];
    }
    __syncthreads();
    if (t < 128) {
        float v = 0.f, q = 0.f;
        #pragma unroll
        for (int rr = 0; rr < 8; ++rr) { v += red[rr*128 + t]; q += red[1024 + rr*128 + t]; }
        atomicAdd(&stats[t], v);
        atomicAdd(&stats[128 + t], q);
    }
}

__global__ void finalize_kernel(const float* __restrict__ stats,
                                const float* __restrict__ gamma,
                                const float* __restrict__ beta,
                                float* __restrict__ sbout,
                                const int* __restrict__ cnt)
{
    int c = threadIdx.x;   // 128
    float n = (float)(*cnt);
    float mean = stats[c] / n;
    float var  = stats[128 + c] / n - mean*mean;
    var = fmaxf(var, 0.f);
    float scale = gamma[c] * rsqrtf(var + EPS_BN);
    sbout[c]       = scale;
    sbout[128 + c] = beta[c] - mean*scale;
}

// out1 <- m1 ? relu(out1*sc+bi) : 0   (bf16 in-place)
__global__ __launch_bounds__(256) void bnrelu_kernel(ushort* __restrict__ o,
                                                     const uchar* __restrict__ m1,
                                                     const float* __restrict__ sb)
{
    int idx = blockIdx.x * 256 + threadIdx.x;   // 1,048,576 chunks of 8
    int px = idx >> 4;
    int c0 = (idx & 15) * 8;
    short8 r = {0,0,0,0,0,0,0,0};
    if (m1[px]) {
        short8 v = *(const short8*)(o + (size_t)px*128 + c0);
        #pragma unroll
        for (int j = 0; j < 8; ++j) {
            float f = fmaf(bf2f((ushort)v[j]), sb[c0+j], sb[128+c0+j]);
            r[j] = (short)f2bf(fmaxf(f, 0.f));
        }
    }
    *(short8*)(o + (size_t)px*128 + c0) = r;
}

// d_out <- m1 ? raw*sc2+bi2 : 0 (f32 in-place)
__global__ __launch_bounds__(256) void apply_kernel(float* __restrict__ out,
                                                    const uchar* __restrict__ m1,
                                                    const float* __restrict__ sb)
{
    int idx4 = blockIdx.x * 256 + threadIdx.x;   // 2,097,152 float4s
    int pos = idx4 >> 5;
    int c4  = (idx4 & 31) << 2;
    float4 v = ((const float4*)out)[idx4];
    float4 r = make_float4(0.f, 0.f, 0.f, 0.f);
    if (m1[pos]) {
        r.x = fmaf(v.x, sb[c4+0], sb[128+c4+0]);
        r.y = fmaf(v.y, sb[c4+1], sb[128+c4+1]);
        r.z = fmaf(v.z, sb[c4+2], sb[128+c4+2]);
        r.w = fmaf(v.w, sb[c4+3], sb[128+c4+3]);
    }
    ((float4*)out)[idx4] = r;
}

extern "C" void kernel_launch(void* const* d_in, const int* in_sizes, int n_in,
                              void* d_out, int out_size, void* d_ws, size_t ws_size,
                              hipStream_t stream)
{
    const float* x      = (const float*)d_in[0];
    const int*   mask   = (const int*)d_in[1];
    const float* w1     = (const float*)d_in[2];
    const float* gamma1 = (const float*)d_in[3];
    const float* beta1  = (const float*)d_in[4];
    const float* w2     = (const float*)d_in[5];
    const float* gamma2 = (const float*)d_in[6];
    const float* beta2  = (const float*)d_in[7];

    // workspace (~17.3 MB)
    ushort* out1 = (ushort*)d_ws;                    // 65536*128 bf16
    ushort* w1T  = out1 + 8388608;                   // 9*128*64
    ushort* w2T  = w1T + 73728;                      // 9*128*128
    float* stats = (float*)(w2T + 147456);           // 512 (256 per BN)
    float* sb    = stats + 512;                      // 512 (256 per BN)
    int*   cnt   = (int*)(sb + 512);                 // 4
    ushort* zp   = (ushort*)(cnt + 4);               // 128 (zero page, 256B)
    uchar* m1    = (uchar*)(zp + 128);               // 65536

    // xb (masked bf16 input, 33.55 MB) lives in d_out; consumed by conv1
    // before conv2 overwrites d_out with raw f32 output.
    ushort* xb = (ushort*)d_out;
    float*  out = (float*)d_out;

    // zero stats + sb + cnt + zp (contiguous)
    hipMemsetAsync(stats, 0, 1024*sizeof(float) + 4*sizeof(int) + 256, stream);

    mask_kernel <<<256,  256, 0, stream>>>(mask, m1, cnt);
    xcvt_kernel <<<8192, 256, 0, stream>>>(x, mask, xb);
    wcvt_kernel <<<864,  256, 0, stream>>>(w1, w2, w1T, w2T);
    conv1_mfma  <<<1024, 256, 0, stream>>>(xb, w1T, zp, m1, out1, stats);
    finalize_kernel<<<1, 128, 0, stream>>>(stats, gamma1, beta1, sb, cnt);
    bnrelu_kernel<<<4096,256, 0, stream>>>(out1, m1, sb);
    conv2_mfma  <<<1024, 256, 0, stream>>>(out1, w2T, zp, m1, out, stats + 256);
    finalize_kernel<<<1, 128, 0, stream>>>(stats + 256, gamma2, beta2, sb + 256, cnt);
    apply_kernel<<<8192, 256, 0, stream>>>(out, m1, sb + 256);
}

// Round 10
// 138.225 us; speedup vs baseline: 1.0442x; 1.0442x over previous
//
#include <hip/hip_runtime.h>

#define EPS_BN 1e-5f
#define MFMA16 __builtin_amdgcn_mfma_f32_16x16x32_bf16

typedef unsigned char uchar;
typedef short short8 __attribute__((ext_vector_type(8)));
typedef float f32x4 __attribute__((ext_vector_type(4)));

__device__ __forceinline__ ushort f2bf(float f) {
    unsigned u = __float_as_uint(f);
    return (ushort)((u + 0x7FFFu + ((u >> 16) & 1u)) >> 16);   // RNE
}
__device__ __forceinline__ float bf2f(ushort h) {
    return __uint_as_float(((unsigned)h) << 16);
}
// async global->LDS, 16B per lane; lds dest = wave-uniform base + lane*16
__device__ __forceinline__ void gload_lds16(const void* g, void* l) {
    __builtin_amdgcn_global_load_lds(
        (const __attribute__((address_space(1))) void*)g,
        (__attribute__((address_space(3))) void*)l, 16, 0, 0);
}

// ---------------------------------------------------------------------------
// x[4,256,256,64] f32, mask[4,256,256] i32 (active==0), w1[3,3,64,128],
// w2[3,3,128,128], out[4,128,128,128] f32.
// Convs: implicit GEMM, M=128px x N=128co per block (grid 512), BK=64,
// SINGLE-buffer 32KB LDS + 2 barriers/K-step, launch_bounds(256,4)
// -> 4 blocks/CU TLP covers the staging drain (m97/m114 structure).
// conv1 fuses the x->bf16 mask+convert into A staging (reg path, ds_write
// with dest-swizzle); B via global_load_lds with source-swizzle.
// LDS layout: LDS[row][c] (16B chunks) holds G[row][c ^ (row&7)];
// frag read byte = (row*128 + ks*64 + lg*16) ^ ((row&7)<<4).
// MFMA maps (mfma_f32_16x16x32_bf16):
//   A: lane(lr,lg)=lr+16*lg holds A[row=lr][k=lg*8..+8)
//   B: lane holds B[k=lg*8..+8)[col=lr]; weights [co][ci] so co=col
//   D: lane holds D[row=lg*4+r][col=lr], r=0..3
// ---------------------------------------------------------------------------

__global__ __launch_bounds__(256) void mask_kernel(const int* __restrict__ mask,
                                                   uchar* __restrict__ m1,
                                                   int* __restrict__ cnt)
{
    int idx = blockIdx.x * 256 + threadIdx.x;   // 65536
    int ow = idx & 127;
    int oh = (idx >> 7) & 127;
    int b  = idx >> 14;
    bool act = false;
    #pragma unroll
    for (int kh = 0; kh < 3; ++kh) {
        int ih = 2*oh - 1 + kh;
        if ((unsigned)ih >= 256u) continue;
        #pragma unroll
        for (int kw = 0; kw < 3; ++kw) {
            int iw = 2*ow - 1 + kw;
            if ((unsigned)iw >= 256u) continue;
            if (mask[(b*256 + ih)*256 + iw] == 0) act = true;
        }
    }
    m1[idx] = act ? 1 : 0;
    unsigned long long bal = __ballot(act);
    if ((threadIdx.x & 63) == 0)
        atomicAdd(cnt, (int)__popcll(bal));
}

// weights -> bf16, transposed to [kh*3+kw][co][ci]
__global__ __launch_bounds__(256) void wcvt_kernel(const float* __restrict__ w1,
                                                   const float* __restrict__ w2,
                                                   ushort* __restrict__ w1T,
                                                   ushort* __restrict__ w2T)
{
    int idx = blockIdx.x * 256 + threadIdx.x;   // 221184 total
    if (idx < 73728) {                          // 9*128*64
        int ci = idx & 63;
        int co = (idx >> 6) & 127;
        int s  = idx >> 13;
        w1T[idx] = f2bf(w1[(s*64 + ci)*128 + co]);
    } else if (idx < 221184) {
        int i  = idx - 73728;                   // 9*128*128
        int ci = i & 127;
        int co = (i >> 7) & 127;
        int s  = i >> 14;
        w2T[i] = f2bf(w2[(s*128 + ci)*128 + co]);
    }
}

// conv1: 3x3 s2, 64->128, reads x f32 + mask directly (xcvt fused).
// Block = output row (b,oh): 128px x 128co. K = 9 steps x BK=64.
__global__ __launch_bounds__(256, 4) void conv1_mfma(const float* __restrict__ x,
                                                     const int* __restrict__ mask,
                                                     const ushort* __restrict__ w1T,
                                                     const uchar* __restrict__ m1,
                                                     ushort* __restrict__ out1,
                                                     float* __restrict__ stats)
{
    __shared__ ushort At[8192];   // 16KB [128px][64ci] swizzled
    __shared__ ushort Bt[8192];   // 16KB [128co][64ci] swizzled

    const int t     = threadIdx.x;
    const int lane  = t & 63;
    const int wv    = t >> 6;
    const int wbase = t & ~63;
    const int blk   = blockIdx.x;    // 512 = b*128 + oh
    const int oh    = blk & 127;
    const int b     = blk >> 7;

    const int wm = wv >> 1, wn = wv & 1;     // wave: 64px x 64co
    const int lr = lane & 15, lg = lane >> 4;

    // ---- hoisted staging geometry ----
    const int p0 = t >> 3;                    // px = r*32 + p0
    const int cd = t & 7;                     // A dest chunk (dest-swizzled)
    const float* xrow[3];
    const int*   mrow[3];
    bool rok[3];
    #pragma unroll
    for (int kh = 0; kh < 3; ++kh) {
        int ih  = 2*oh + kh - 1;
        rok[kh] = ((unsigned)ih < 256u);
        int ihc = ih < 0 ? 0 : (ih > 255 ? 255 : ih);
        xrow[kh] = x + (size_t)(b*256 + ihc)*256*64 + cd*8;
        mrow[kh] = mask + (size_t)(b*256 + ihc)*256;
    }
    const int ldsA0 = ((p0*128 + cd*16) ^ ((p0 & 7) << 4));   // r adds 32*128
    // B: gload source pre-swizzled; dest linear by thread
    const int co0  = t >> 3;                  // co = r*32 + co0
    const int bcs  = (t & 7) ^ (co0 & 7);
    const ushort* pB0 = w1T + (size_t)co0*64 + bcs*8;

    auto stageA = [&](int s) {
        const int kh = s / 3, kw = s % 3;
        #pragma unroll
        for (int r = 0; r < 4; ++r) {
            int px = r*32 + p0;
            int iw = 2*px + kw - 1;
            short8 v = {0,0,0,0,0,0,0,0};
            if (rok[kh] && (unsigned)iw < 256u && mrow[kh][iw] == 0) {
                const float* p = xrow[kh] + (size_t)iw*64;
                float4 fa = *(const float4*)p;
                float4 fb = *(const float4*)(p + 4);
                v[0]=(short)f2bf(fa.x); v[1]=(short)f2bf(fa.y);
                v[2]=(short)f2bf(fa.z); v[3]=(short)f2bf(fa.w);
                v[4]=(short)f2bf(fb.x); v[5]=(short)f2bf(fb.y);
                v[6]=(short)f2bf(fb.z); v[7]=(short)f2bf(fb.w);
            }
            *(short8*)((char*)At + (ldsA0 + r*4096)) = v;   // 32*128B
        }
    };
    auto dmaB = [&](int s) {
        #pragma unroll
        for (int r = 0; r < 4; ++r)
            gload_lds16(pB0 + (size_t)s*8192 + r*2048,
                        &Bt[(size_t)(r*256 + wbase)*8]);
    };

    f32x4 acc[4][4];
    #pragma unroll
    for (int mi = 0; mi < 4; ++mi)
        #pragma unroll
        for (int ni = 0; ni < 4; ++ni)
            acc[mi][ni] = (f32x4){0.f, 0.f, 0.f, 0.f};

    #pragma unroll
    for (int kt = 0; kt < 9; ++kt) {
        if (kt) __syncthreads();          // prev compute done, LDS free
        stageA(kt);
        dmaB(kt);
        __syncthreads();                  // drain vm+lgkm (compiler-emitted)
        const char* Ab = (const char*)At;
        const char* Bb = (const char*)Bt;
        #pragma unroll
        for (int ks = 0; ks < 2; ++ks) {
            short8 af[4], bfr[4];
            #pragma unroll
            for (int mi = 0; mi < 4; ++mi) {
                int row = wm*64 + mi*16 + lr;
                af[mi] = *(const short8*)(Ab + ((row*128 + ks*64 + lg*16) ^ ((row & 7) << 4)));
            }
            #pragma unroll
            for (int ni = 0; ni < 4; ++ni) {
                int co = wn*64 + ni*16 + lr;
                bfr[ni] = *(const short8*)(Bb + ((co*128 + ks*64 + lg*16) ^ ((co & 7) << 4)));
            }
            #pragma unroll
            for (int mi = 0; mi < 4; ++mi)
                #pragma unroll
                for (int ni = 0; ni < 4; ++ni)
                    acc[mi][ni] = MFMA16(af[mi], bfr[ni], acc[mi][ni], 0, 0, 0);
        }
    }

    const size_t pixbase = (size_t)blk * 128;
    #pragma unroll
    for (int mi = 0; mi < 4; ++mi) {
        #pragma unroll
        for (int ni = 0; ni < 4; ++ni) {
            int px = wm*64 + mi*16 + lg*4;
            int co = wn*64 + ni*16 + lr;
            #pragma unroll
            for (int r = 0; r < 4; ++r)
                out1[(pixbase + px + r)*128 + co] = f2bf(acc[mi][ni][r]);
        }
    }

    // ---- fused BN1 stats ----
    float s4[4] = {0.f,0.f,0.f,0.f}, q4[4] = {0.f,0.f,0.f,0.f};
    #pragma unroll
    for (int mi = 0; mi < 4; ++mi) {
        const uchar* mp = m1 + pixbase + wm*64 + mi*16 + lg*4;
        #pragma unroll
        for (int r = 0; r < 4; ++r) {
            float a = mp[r] ? 1.f : 0.f;
            #pragma unroll
            for (int ni = 0; ni < 4; ++ni) {
                float av = a * acc[mi][ni][r];
                s4[ni] += av;
                q4[ni] += av * acc[mi][ni][r];
            }
        }
    }
    __syncthreads();                      // all waves done reading At
    float* red = (float*)At;              // 8KB of the 16KB A buffer
    const int rrow = wm*4 + lg;
    #pragma unroll
    for (int ni = 0; ni < 4; ++ni) {
        red[rrow*128 + wn*64 + ni*16 + lr]        = s4[ni];
        red[1024 + rrow*128 + wn*64 + ni*16 + lr] = q4[ni];
    }
    __syncthreads();
    if (t < 128) {
        float v = 0.f, q = 0.f;
        #pragma unroll
        for (int rr = 0; rr < 8; ++rr) { v += red[rr*128 + t]; q += red[1024 + rr*128 + t]; }
        atomicAdd(&stats[t], v);
        atomicAdd(&stats[128 + t], q);
    }
}

// conv2: 3x3 s1, 128->128 on bnrelu'd out1. Block = 128px x 128co.
// K = 18 steps (9 taps x 2 ci-halves) x BK=64. A+B via gload_lds.
__global__ __launch_bounds__(256, 4) void conv2_mfma(const ushort* __restrict__ a,
                                                     const ushort* __restrict__ w2T,
                                                     const ushort* __restrict__ zp,
                                                     const uchar* __restrict__ m1,
                                                     float* __restrict__ outraw,
                                                     float* __restrict__ stats)
{
    __shared__ ushort At[8192];
    __shared__ ushort Bt[8192];

    const int t     = threadIdx.x;
    const int lane  = t & 63;
    const int wv    = t >> 6;
    const int wbase = t & ~63;
    const int blk   = blockIdx.x;    // 512 = b*128 + oh
    const int oh    = blk & 127;
    const int b     = blk >> 7;

    const int wm = wv >> 1, wn = wv & 1;
    const int lr = lane & 15, lg = lane >> 4;

    // A: px = r*32 + p0, chunk cd; gload source pre-swizzled
    const int p0  = t >> 3;
    const int cs  = (t & 7) ^ (p0 & 7);     // (r*32+p0)&7 == p0&7
    const ushort* arow[3];
    bool rok[3];
    #pragma unroll
    for (int kh = 0; kh < 3; ++kh) {
        int ih  = oh + kh - 1;
        rok[kh] = ((unsigned)ih < 128u);
        int ihc = ih < 0 ? 0 : (ih > 127 ? 127 : ih);
        arow[kh] = a + (size_t)(b*128 + ihc)*128*128 + cs*8;
    }
    const int aoff0 = (p0 - 1) * 128;        // + r*4096 + kw*128 + h*64
    const ushort* pB0 = w2T + (size_t)(t >> 3)*128 + ((t & 7) ^ ((t >> 3) & 7))*8;

    auto dma = [&](int kt) {
        const int s = kt >> 1, h = kt & 1;
        const int kh = s / 3, kw = s % 3;
        #pragma unroll
        for (int r = 0; r < 4; ++r) {
            int px = r*32 + p0;
            bool ok = rok[kh] && ((unsigned)(px + kw - 1) < 128u);
            const ushort* g = ok ? arow[kh] + aoff0 + r*4096 + kw*128 + h*64 : zp;
            gload_lds16(g, &At[(size_t)(r*256 + wbase)*8]);
        }
        #pragma unroll
        for (int r = 0; r < 4; ++r)
            gload_lds16(pB0 + (size_t)s*16384 + h*64 + r*4096,
                        &Bt[(size_t)(r*256 + wbase)*8]);
    };

    f32x4 acc[4][4];
    #pragma unroll
    for (int mi = 0; mi < 4; ++mi)
        #pragma unroll
        for (int ni = 0; ni < 4; ++ni)
            acc[mi][ni] = (f32x4){0.f, 0.f, 0.f, 0.f};

    #pragma unroll
    for (int kt = 0; kt < 18; ++kt) {
        if (kt) __syncthreads();
        dma(kt);
        __syncthreads();
        const char* Ab = (const char*)At;
        const char* Bb = (const char*)Bt;
        #pragma unroll
        for (int ks = 0; ks < 2; ++ks) {
            short8 af[4], bfr[4];
            #pragma unroll
            for (int mi = 0; mi < 4; ++mi) {
                int row = wm*64 + mi*16 + lr;
                af[mi] = *(const short8*)(Ab + ((row*128 + ks*64 + lg*16) ^ ((row & 7) << 4)));
            }
            #pragma unroll
            for (int ni = 0; ni < 4; ++ni) {
                int co = wn*64 + ni*16 + lr;
                bfr[ni] = *(const short8*)(Bb + ((co*128 + ks*64 + lg*16) ^ ((co & 7) << 4)));
            }
            #pragma unroll
            for (int mi = 0; mi < 4; ++mi)
                #pragma unroll
                for (int ni = 0; ni < 4; ++ni)
                    acc[mi][ni] = MFMA16(af[mi], bfr[ni], acc[mi][ni], 0, 0, 0);
        }
    }

    const size_t pixbase = (size_t)blk * 128;
    #pragma unroll
    for (int mi = 0; mi < 4; ++mi) {
        #pragma unroll
        for (int ni = 0; ni < 4; ++ni) {
            int px = wm*64 + mi*16 + lg*4;
            int co = wn*64 + ni*16 + lr;
            #pragma unroll
            for (int r = 0; r < 4; ++r)
                outraw[(pixbase + px + r)*128 + co] = acc[mi][ni][r];
        }
    }

    // ---- fused BN2 stats ----
    float s4[4] = {0.f,0.f,0.f,0.f}, q4[4] = {0.f,0.f,0.f,0.f};
    #pragma unroll
    for (int mi = 0; mi < 4; ++mi) {
        const uchar* mp = m1 + pixbase + wm*64 + mi*16 + lg*4;
        #pragma unroll
        for (int r = 0; r < 4; ++r) {
            float av0 = mp[r] ? 1.f : 0.f;
            #pragma unroll
            for (int ni = 0; ni < 4; ++ni) {
                float av = av0 * acc[mi][ni][r];
                s4[ni] += av;
                q4[ni] += av * acc[mi][ni][r];
            }
        }
    }
    __syncthreads();
    float* red = (float*)At;
    const int rrow = wm*4 + lg;
    #pragma unroll
    for (int ni = 0; ni < 4; ++ni) {
        red[rrow*128 + wn*64 + ni*16 + lr]        = s4[ni];
        red[1024 + rrow*128 + wn*64 + ni*16 + lr] = q4[ni];
    }
    __syncthreads();
    if (t < 128) {
        float v = 0.f, q = 0.f;
        #pragma unroll
        for (int rr = 0; rr < 8; ++rr) { v += red[rr*128 + t]; q += red[1024 + rr*128 + t]; }
        atomicAdd(&stats[t], v);
        atomicAdd(&stats[128 + t], q);
    }
}

__global__ void finalize_kernel(const float* __restrict__ stats,
                                const float* __restrict__ gamma,
                                const float* __restrict__ beta,
                                float* __restrict__ sbout,
                                const int* __restrict__ cnt)
{
    int c = threadIdx.x;   // 128
    float n = (float)(*cnt);
    float mean = stats[c] / n;
    float var  = stats[128 + c] / n - mean*mean;
    var = fmaxf(var, 0.f);
    float scale = gamma[c] * rsqrtf(var + EPS_BN);
    sbout[c]       = scale;
    sbout[128 + c] = beta[c] - mean*scale;
}

// out1 <- m1 ? relu(out1*sc+bi) : 0   (bf16 in-place)
__global__ __launch_bounds__(256) void bnrelu_kernel(ushort* __restrict__ o,
                                                     const uchar* __restrict__ m1,
                                                     const float* __restrict__ sb)
{
    int idx = blockIdx.x * 256 + threadIdx.x;   // 1,048,576 chunks of 8
    int px = idx >> 4;
    int c0 = (idx & 15) * 8;
    short8 r = {0,0,0,0,0,0,0,0};
    if (m1[px]) {
        short8 v = *(const short8*)(o + (size_t)px*128 + c0);
        #pragma unroll
        for (int j = 0; j < 8; ++j) {
            float f = fmaf(bf2f((ushort)v[j]), sb[c0+j], sb[128+c0+j]);
            r[j] = (short)f2bf(fmaxf(f, 0.f));
        }
    }
    *(short8*)(o + (size_t)px*128 + c0) = r;
}

// d_out <- m1 ? raw*sc2+bi2 : 0 (f32 in-place)
__global__ __launch_bounds__(256) void apply_kernel(float* __restrict__ out,
                                                    const uchar* __restrict__ m1,
                                                    const float* __restrict__ sb)
{
    int idx4 = blockIdx.x * 256 + threadIdx.x;   // 2,097,152 float4s
    int pos = idx4 >> 5;
    int c4  = (idx4 & 31) << 2;
    float4 v = ((const float4*)out)[idx4];
    float4 r = make_float4(0.f, 0.f, 0.f, 0.f);
    if (m1[pos]) {
        r.x = fmaf(v.x, sb[c4+0], sb[128+c4+0]);
        r.y = fmaf(v.y, sb[c4+1], sb[128+c4+1]);
        r.z = fmaf(v.z, sb[c4+2], sb[128+c4+2]);
        r.w = fmaf(v.w, sb[c4+3], sb[128+c4+3]);
    }
    ((float4*)out)[idx4] = r;
}

extern "C" void kernel_launch(void* const* d_in, const int* in_sizes, int n_in,
                              void* d_out, int out_size, void* d_ws, size_t ws_size,
                              hipStream_t stream)
{
    const float* x      = (const float*)d_in[0];
    const int*   mask   = (const int*)d_in[1];
    const float* w1     = (const float*)d_in[2];
    const float* gamma1 = (const float*)d_in[3];
    const float* beta1  = (const float*)d_in[4];
    const float* w2     = (const float*)d_in[5];
    const float* gamma2 = (const float*)d_in[6];
    const float* beta2  = (const float*)d_in[7];

    // workspace (~17.3 MB)
    ushort* out1 = (ushort*)d_ws;                    // 65536*128 bf16
    ushort* w1T  = out1 + 8388608;                   // 9*128*64
    ushort* w2T  = w1T + 73728;                      // 9*128*128
    float* stats = (float*)(w2T + 147456);           // 512 (256 per BN)
    float* sb    = stats + 512;                      // 512 (256 per BN)
    int*   cnt   = (int*)(sb + 512);                 // 4
    ushort* zp   = (ushort*)(cnt + 4);               // 128 (zero page, 256B)
    uchar* m1    = (uchar*)(zp + 128);               // 65536

    float* out = (float*)d_out;

    // zero stats + sb + cnt + zp (contiguous)
    hipMemsetAsync(stats, 0, 1024*sizeof(float) + 4*sizeof(int) + 256, stream);

    mask_kernel <<<256,  256, 0, stream>>>(mask, m1, cnt);
    wcvt_kernel <<<864,  256, 0, stream>>>(w1, w2, w1T, w2T);
    conv1_mfma  <<<512,  256, 0, stream>>>(x, mask, w1T, m1, out1, stats);
    finalize_kernel<<<1, 128, 0, stream>>>(stats, gamma1, beta1, sb, cnt);
    bnrelu_kernel<<<4096,256, 0, stream>>>(out1, m1, sb);
    conv2_mfma  <<<512,  256, 0, stream>>>(out1, w2T, zp, m1, out, stats + 256);
    finalize_kernel<<<1, 128, 0, stream>>>(stats + 256, gamma2, beta2, sb + 256, cnt);
    apply_kernel<<<8192, 256, 0, stream>>>(out, m1, sb + 256);
}

// Round 11
// 133.804 us; speedup vs baseline: 1.0787x; 1.0330x over previous
//
#include <hip/hip_runtime.h>

#define EPS_BN 1e-5f
#define MFMA16 __builtin_amdgcn_mfma_f32_16x16x32_bf16

typedef unsigned char uchar;
typedef short short8 __attribute__((ext_vector_type(8)));
typedef float f32x4 __attribute__((ext_vector_type(4)));

__device__ __forceinline__ ushort f2bf(float f) {
    unsigned u = __float_as_uint(f);
    return (ushort)((u + 0x7FFFu + ((u >> 16) & 1u)) >> 16);   // RNE
}
__device__ __forceinline__ float bf2f(ushort h) {
    return __uint_as_float(((unsigned)h) << 16);
}
// async global->LDS, 16B/lane; lds dest = wave-uniform base + lane*16
__device__ __forceinline__ void gload_lds16(const void* g, void* l) {
    __builtin_amdgcn_global_load_lds(
        (const __attribute__((address_space(1))) void*)g,
        (__attribute__((address_space(3))) void*)l, 16, 0, 0);
}

// ---------------------------------------------------------------------------
// x[4,256,256,64] f32, mask[4,256,256] i32 (active==0), w1[3,3,64,128],
// w2[3,3,128,128], out[4,128,128,128] f32.
// Conv structure (R11): A-halo staged ONCE per kh into LDS (ds_write, XOR
// swizzled both sides); B streamed per tap via gload_lds dbuf with
// prefetch-issued-BEFORE-compute (R8-proven overlap). M=64px tile, grid
// 1024 (XCD-chunked swizzle), ~50KB LDS -> 3 blocks/CU.
// conv1 fuses mask+f32->bf16 into its halo staging; conv2 fuses BN1+ReLU+m1.
// MFMA maps (mfma_f32_16x16x32_bf16):
//   A: lane(lr,lg)=lr+16*lg holds A[row=lr][k=lg*8..+8)
//   B: lane holds B[k=lg*8..+8)[col=lr]; weights [co][ci] so co=col
//   D: lane holds D[row=lg*4+r][col=lr], r=0..3
// ---------------------------------------------------------------------------

__global__ __launch_bounds__(256) void mask_kernel(const int* __restrict__ mask,
                                                   uchar* __restrict__ m1,
                                                   int* __restrict__ cnt)
{
    int idx = blockIdx.x * 256 + threadIdx.x;   // 65536
    int ow = idx & 127;
    int oh = (idx >> 7) & 127;
    int b  = idx >> 14;
    bool act = false;
    #pragma unroll
    for (int kh = 0; kh < 3; ++kh) {
        int ih = 2*oh - 1 + kh;
        if ((unsigned)ih >= 256u) continue;
        #pragma unroll
        for (int kw = 0; kw < 3; ++kw) {
            int iw = 2*ow - 1 + kw;
            if ((unsigned)iw >= 256u) continue;
            if (mask[(b*256 + ih)*256 + iw] == 0) act = true;
        }
    }
    m1[idx] = act ? 1 : 0;
    unsigned long long bal = __ballot(act);
    if ((threadIdx.x & 63) == 0)
        atomicAdd(cnt, (int)__popcll(bal));
}

// weights -> bf16, transposed to [kh*3+kw][co][ci]
__global__ __launch_bounds__(256) void wcvt_kernel(const float* __restrict__ w1,
                                                   const float* __restrict__ w2,
                                                   ushort* __restrict__ w1T,
                                                   ushort* __restrict__ w2T)
{
    int idx = blockIdx.x * 256 + threadIdx.x;   // 221184 total
    if (idx < 73728) {                          // 9*128*64
        int ci = idx & 63;
        int co = (idx >> 6) & 127;
        int s  = idx >> 13;
        w1T[idx] = f2bf(w1[(s*64 + ci)*128 + co]);
    } else if (idx < 221184) {
        int i  = idx - 73728;                   // 9*128*128
        int ci = i & 127;
        int co = (i >> 7) & 127;
        int s  = i >> 14;
        w2T[i] = f2bf(w2[(s*128 + ci)*128 + co]);
    }
}

// conv1: 3x3 s2, 64->128, reads x f32 + mask (xcvt fused into halo staging).
// Block = 64px x 128co. A-halo plane [132 cols][64ci] per kh; B dbuf 16KBx2.
__global__ __launch_bounds__(256, 3) void conv1_mfma(const float* __restrict__ x,
                                                     const int* __restrict__ mask,
                                                     const ushort* __restrict__ w1T,
                                                     const uchar* __restrict__ m1,
                                                     ushort* __restrict__ out1,
                                                     float* __restrict__ stats)
{
    __shared__ ushort Ah[132 * 64];     // 16,896 B: swizzled ^(((c>>1)&7)<<4)
    __shared__ ushort Bd[2][8192];      // 16 KB each: [128co][64ci] swizzled

    const int t     = threadIdx.x;
    const int lane  = t & 63;
    const int wv    = t >> 6;
    const int wbase = t & ~63;
    const int bid   = blockIdx.x;
    const int L     = (bid & 7) * 128 + (bid >> 3);   // XCD-chunked, bijective
    const int half  = L & 1;
    const int oh    = (L >> 1) & 127;
    const int b     = L >> 8;
    const int ow0   = half * 64;
    const int iw0   = 2*ow0 - 1;

    const int wm = wv >> 1, wn = wv & 1;     // wave: 32px x 64co
    const int lr = lane & 15, lg = lane >> 4;

    auto stageA = [&](int kh) {
        int ih  = 2*oh + kh - 1;
        bool rok = ((unsigned)ih < 256u);
        int ihc = ih < 0 ? 0 : (ih > 255 ? 255 : ih);
        const float* xr = x + (size_t)(b*256 + ihc) * 256 * 64;
        const int*   mr = mask + (size_t)(b*256 + ihc) * 256;
        for (int idx = t; idx < 1056; idx += 256) {   // 132 cols x 8 chunks
            int c = idx >> 3, k = idx & 7;
            int iw = iw0 + c;
            short8 v = {0,0,0,0,0,0,0,0};
            if (rok && (unsigned)iw < 256u && mr[iw] == 0) {
                const float* p = xr + (size_t)iw*64 + k*8;
                float4 fa = *(const float4*)p;
                float4 fb = *(const float4*)(p + 4);
                v[0]=(short)f2bf(fa.x); v[1]=(short)f2bf(fa.y);
                v[2]=(short)f2bf(fa.z); v[3]=(short)f2bf(fa.w);
                v[4]=(short)f2bf(fb.x); v[5]=(short)f2bf(fb.y);
                v[6]=(short)f2bf(fb.z); v[7]=(short)f2bf(fb.w);
            }
            int ad = (c*128 + k*16) ^ ((((unsigned)c >> 1) & 7) << 4);
            *(short8*)((char*)Ah + ad) = v;
        }
    };
    const int coB = t >> 3;                  // co = r*32 + coB
    const int dB  = t & 7;
    auto dmaB = [&](int buf, int tap) {
        #pragma unroll
        for (int r = 0; r < 4; ++r) {
            int co = r*32 + coB;
            const ushort* g = w1T + (size_t)tap*8192 + (size_t)co*64
                            + ((dB ^ (co & 7)) << 3);
            gload_lds16(g, &Bd[buf][(size_t)(r*256 + wbase)*8]);
        }
    };

    f32x4 acc[2][4];
    #pragma unroll
    for (int mi = 0; mi < 2; ++mi)
        #pragma unroll
        for (int ni = 0; ni < 4; ++ni)
            acc[mi][ni] = (f32x4){0.f, 0.f, 0.f, 0.f};

    stageA(0);
    dmaB(0, 0);
    __syncthreads();
    #pragma unroll
    for (int q = 0; q < 9; ++q) {
        const int kw = q % 3, cur = q & 1;
        if (q < 8) dmaB(cur ^ 1, q + 1);     // prefetch BEFORE compute
        const char* Ab = (const char*)Ah;
        const char* Bb = (const char*)Bd[cur];
        #pragma unroll
        for (int ks = 0; ks < 2; ++ks) {
            short8 af[2], bfr[4];
            #pragma unroll
            for (int mi = 0; mi < 2; ++mi) {
                int c = 2*(wm*32 + mi*16 + lr) + kw;
                af[mi] = *(const short8*)(Ab +
                    ((c*128 + ks*64 + lg*16) ^ ((((unsigned)c >> 1) & 7) << 4)));
            }
            #pragma unroll
            for (int ni = 0; ni < 4; ++ni) {
                int co = wn*64 + ni*16 + lr;
                bfr[ni] = *(const short8*)(Bb +
                    ((co*128 + ks*64 + lg*16) ^ ((co & 7) << 4)));
            }
            #pragma unroll
            for (int mi = 0; mi < 2; ++mi)
                #pragma unroll
                for (int ni = 0; ni < 4; ++ni)
                    acc[mi][ni] = MFMA16(af[mi], bfr[ni], acc[mi][ni], 0, 0, 0);
        }
        __syncthreads();                     // drains prefetch + read-done
        if (kw == 2 && q < 8) {              // new kh: restage halo plane
            stageA(q/3 + 1);
            __syncthreads();
        }
    }

    const size_t pixbase = (size_t)(b*128 + oh) * 128 + ow0;
    #pragma unroll
    for (int mi = 0; mi < 2; ++mi) {
        #pragma unroll
        for (int ni = 0; ni < 4; ++ni) {
            int px = wm*32 + mi*16 + lg*4;
            int co = wn*64 + ni*16 + lr;
            #pragma unroll
            for (int r = 0; r < 4; ++r)
                out1[(pixbase + px + r)*128 + co] = f2bf(acc[mi][ni][r]);
        }
    }

    // ---- fused BN1 stats ----
    float s4[4] = {0.f,0.f,0.f,0.f}, q4[4] = {0.f,0.f,0.f,0.f};
    #pragma unroll
    for (int mi = 0; mi < 2; ++mi) {
        const uchar* mp = m1 + pixbase + wm*32 + mi*16 + lg*4;
        #pragma unroll
        for (int r = 0; r < 4; ++r) {
            float a = mp[r] ? 1.f : 0.f;
            #pragma unroll
            for (int ni = 0; ni < 4; ++ni) {
                float av = a * acc[mi][ni][r];
                s4[ni] += av;
                q4[ni] += av * acc[mi][ni][r];
            }
        }
    }
    float* red = (float*)Ah;                 // safe: barrier ended q-loop
    const int rrow = wm*4 + lg;
    #pragma unroll
    for (int ni = 0; ni < 4; ++ni) {
        red[rrow*128 + wn*64 + ni*16 + lr]        = s4[ni];
        red[1024 + rrow*128 + wn*64 + ni*16 + lr] = q4[ni];
    }
    __syncthreads();
    if (t < 128) {
        float v = 0.f, q = 0.f;
        #pragma unroll
        for (int rr = 0; rr < 8; ++rr) { v += red[rr*128 + t]; q += red[1024 + rr*128 + t]; }
        atomicAdd(&stats[t], v);
        atomicAdd(&stats[128 + t], q);
    }
}

// conv2: 3x3 s1, 128->128 on RAW out1 (BN1+ReLU+m1 fused into halo staging).
// Block = 64px x 128co. A-halo [66 cols][128ci] per kh; B dbuf 16KBx2
// per (tap, ci-half); 18 B-steps total.
__global__ __launch_bounds__(256, 3) void conv2_mfma(const ushort* __restrict__ a,
                                                     const ushort* __restrict__ w2T,
                                                     const uchar* __restrict__ m1,
                                                     const float* __restrict__ sb,
                                                     float* __restrict__ outraw,
                                                     float* __restrict__ stats)
{
    __shared__ ushort Ah[66 * 128];     // 16,896 B: swizzled ^((c&7)<<4)
    __shared__ ushort Bd[2][8192];      // [128co][64ci-half]
    __shared__ float scb[256];          // sc[128], bi[128]

    const int t     = threadIdx.x;
    const int lane  = t & 63;
    const int wv    = t >> 6;
    const int wbase = t & ~63;
    const int bid   = blockIdx.x;
    const int L     = (bid & 7) * 128 + (bid >> 3);
    const int half  = L & 1;
    const int oh    = (L >> 1) & 127;
    const int b     = L >> 8;
    const int ow0   = half * 64;

    const int wm = wv >> 1, wn = wv & 1;
    const int lr = lane & 15, lg = lane >> 4;

    scb[t] = sb[t & 255];               // 256 threads cover 256 entries

    auto stageA = [&](int kh) {
        int ih  = oh + kh - 1;
        bool rok = ((unsigned)ih < 128u);
        int ihc = ih < 0 ? 0 : (ih > 127 ? 127 : ih);
        const ushort* ar = a + (size_t)(b*128 + ihc) * 128 * 128;
        const uchar*  mr = m1 + (size_t)(b*128 + ihc) * 128;
        for (int idx = t; idx < 1056; idx += 256) {   // 66 cols x 16 chunks
            int c = idx >> 4, k = idx & 15;
            int iw = ow0 - 1 + c;
            short8 v = {0,0,0,0,0,0,0,0};
            if (rok && (unsigned)iw < 128u && mr[iw]) {
                short8 rv = *(const short8*)(ar + (size_t)iw*128 + k*8);
                #pragma unroll
                for (int j = 0; j < 8; ++j) {
                    float f = fmaf(bf2f((ushort)rv[j]), scb[k*8 + j], scb[128 + k*8 + j]);
                    v[j] = (short)f2bf(fmaxf(f, 0.f));
                }
            }
            int ad = (c*256 + k*16) ^ ((c & 7) << 4);
            *(short8*)((char*)Ah + ad) = v;
        }
    };
    const int coB = t >> 3;
    const int dB  = t & 7;
    auto dmaB = [&](int buf, int q) {
        const int s = q / 6;                 // tap
        const int j = q % 6;
        const int kw_ = j >> 1, h = j & 1;
        const int tap = s*3 + kw_;           // s is kh here: tap = kh*3+kw
        #pragma unroll
        for (int r = 0; r < 4; ++r) {
            int co = r*32 + coB;
            const ushort* g = w2T + (size_t)tap*16384 + (size_t)co*128 + h*64
                            + ((dB ^ (co & 7)) << 3);
            gload_lds16(g, &Bd[buf][(size_t)(r*256 + wbase)*8]);
        }
    };

    f32x4 acc[2][4];
    #pragma unroll
    for (int mi = 0; mi < 2; ++mi)
        #pragma unroll
        for (int ni = 0; ni < 4; ++ni)
            acc[mi][ni] = (f32x4){0.f, 0.f, 0.f, 0.f};

    __syncthreads();                         // scb visible to all
    stageA(0);
    dmaB(0, 0);
    __syncthreads();
    #pragma unroll
    for (int q = 0; q < 18; ++q) {
        const int j = q % 6;
        const int kw_ = j >> 1, h = j & 1, cur = q & 1;
        if (q < 17) dmaB(cur ^ 1, q + 1);    // prefetch BEFORE compute
        const char* Ab = (const char*)Ah;
        const char* Bb = (const char*)Bd[cur];
        #pragma unroll
        for (int ks = 0; ks < 2; ++ks) {
            short8 af[2], bfr[4];
            #pragma unroll
            for (int mi = 0; mi < 2; ++mi) {
                int c = wm*32 + mi*16 + lr + kw_;
                af[mi] = *(const short8*)(Ab +
                    ((c*256 + h*128 + ks*64 + lg*16) ^ ((c & 7) << 4)));
            }
            #pragma unroll
            for (int ni = 0; ni < 4; ++ni) {
                int co = wn*64 + ni*16 + lr;
                bfr[ni] = *(const short8*)(Bb +
                    ((co*128 + ks*64 + lg*16) ^ ((co & 7) << 4)));
            }
            #pragma unroll
            for (int mi = 0; mi < 2; ++mi)
                #pragma unroll
                for (int ni = 0; ni < 4; ++ni)
                    acc[mi][ni] = MFMA16(af[mi], bfr[ni], acc[mi][ni], 0, 0, 0);
        }
        __syncthreads();
        if (j == 5 && q < 17) {              // new kh: restage halo plane
            stageA(q/6 + 1);
            __syncthreads();
        }
    }

    const size_t pixbase = (size_t)(b*128 + oh) * 128 + ow0;
    #pragma unroll
    for (int mi = 0; mi < 2; ++mi) {
        #pragma unroll
        for (int ni = 0; ni < 4; ++ni) {
            int px = wm*32 + mi*16 + lg*4;
            int co = wn*64 + ni*16 + lr;
            #pragma unroll
            for (int r = 0; r < 4; ++r)
                outraw[(pixbase + px + r)*128 + co] = acc[mi][ni][r];
        }
    }

    // ---- fused BN2 stats ----
    float s4[4] = {0.f,0.f,0.f,0.f}, q4[4] = {0.f,0.f,0.f,0.f};
    #pragma unroll
    for (int mi = 0; mi < 2; ++mi) {
        const uchar* mp = m1 + pixbase + wm*32 + mi*16 + lg*4;
        #pragma unroll
        for (int r = 0; r < 4; ++r) {
            float av0 = mp[r] ? 1.f : 0.f;
            #pragma unroll
            for (int ni = 0; ni < 4; ++ni) {
                float av = av0 * acc[mi][ni][r];
                s4[ni] += av;
                q4[ni] += av * acc[mi][ni][r];
            }
        }
    }
    float* red = (float*)Ah;
    const int rrow = wm*4 + lg;
    #pragma unroll
    for (int ni = 0; ni < 4; ++ni) {
        red[rrow*128 + wn*64 + ni*16 + lr]        = s4[ni];
        red[1024 + rrow*128 + wn*64 + ni*16 + lr] = q4[ni];
    }
    __syncthreads();
    if (t < 128) {
        float v = 0.f, q = 0.f;
        #pragma unroll
        for (int rr = 0; rr < 8; ++rr) { v += red[rr*128 + t]; q += red[1024 + rr*128 + t]; }
        atomicAdd(&stats[t], v);
        atomicAdd(&stats[128 + t], q);
    }
}

__global__ void finalize_kernel(const float* __restrict__ stats,
                                const float* __restrict__ gamma,
                                const float* __restrict__ beta,
                                float* __restrict__ sbout,
                                const int* __restrict__ cnt)
{
    int c = threadIdx.x;   // 128
    float n = (float)(*cnt);
    float mean = stats[c] / n;
    float var  = stats[128 + c] / n - mean*mean;
    var = fmaxf(var, 0.f);
    float scale = gamma[c] * rsqrtf(var + EPS_BN);
    sbout[c]       = scale;
    sbout[128 + c] = beta[c] - mean*scale;
}

// d_out <- m1 ? raw*sc2+bi2 : 0 (f32 in-place)
__global__ __launch_bounds__(256) void apply_kernel(float* __restrict__ out,
                                                    const uchar* __restrict__ m1,
                                                    const float* __restrict__ sb)
{
    int idx4 = blockIdx.x * 256 + threadIdx.x;   // 2,097,152 float4s
    int pos = idx4 >> 5;
    int c4  = (idx4 & 31) << 2;
    float4 v = ((const float4*)out)[idx4];
    float4 r = make_float4(0.f, 0.f, 0.f, 0.f);
    if (m1[pos]) {
        r.x = fmaf(v.x, sb[c4+0], sb[128+c4+0]);
        r.y = fmaf(v.y, sb[c4+1], sb[128+c4+1]);
        r.z = fmaf(v.z, sb[c4+2], sb[128+c4+2]);
        r.w = fmaf(v.w, sb[c4+3], sb[128+c4+3]);
    }
    ((float4*)out)[idx4] = r;
}

extern "C" void kernel_launch(void* const* d_in, const int* in_sizes, int n_in,
                              void* d_out, int out_size, void* d_ws, size_t ws_size,
                              hipStream_t stream)
{
    const float* x      = (const float*)d_in[0];
    const int*   mask   = (const int*)d_in[1];
    const float* w1     = (const float*)d_in[2];
    const float* gamma1 = (const float*)d_in[3];
    const float* beta1  = (const float*)d_in[4];
    const float* w2     = (const float*)d_in[5];
    const float* gamma2 = (const float*)d_in[6];
    const float* beta2  = (const float*)d_in[7];

    // workspace (~17.3 MB)
    ushort* out1 = (ushort*)d_ws;                    // 65536*128 bf16 (raw conv1)
    ushort* w1T  = out1 + 8388608;                   // 9*128*64
    ushort* w2T  = w1T + 73728;                      // 9*128*128
    float* stats = (float*)(w2T + 147456);           // 512 (256 per BN)
    float* sb    = stats + 512;                      // 512 (256 per BN)
    int*   cnt   = (int*)(sb + 512);                 // 4
    uchar* m1    = (uchar*)(cnt + 4);                // 65536

    float* out = (float*)d_out;

    // zero stats + sb + cnt (contiguous)
    hipMemsetAsync(stats, 0, 1024*sizeof(float) + 4*sizeof(int), stream);

    mask_kernel <<<256,  256, 0, stream>>>(mask, m1, cnt);
    wcvt_kernel <<<864,  256, 0, stream>>>(w1, w2, w1T, w2T);
    conv1_mfma  <<<1024, 256, 0, stream>>>(x, mask, w1T, m1, out1, stats);
    finalize_kernel<<<1, 128, 0, stream>>>(stats, gamma1, beta1, sb, cnt);
    conv2_mfma  <<<1024, 256, 0, stream>>>(out1, w2T, m1, sb, out, stats + 256);
    finalize_kernel<<<1, 128, 0, stream>>>(stats + 256, gamma2, beta2, sb + 256, cnt);
    apply_kernel<<<8192, 256, 0, stream>>>(out, m1, sb + 256);
}

// Round 12
// 131.221 us; speedup vs baseline: 1.1000x; 1.0197x over previous
//
#include <hip/hip_runtime.h>

#define EPS_BN 1e-5f
#define MFMA16 __builtin_amdgcn_mfma_f32_16x16x32_bf16
#define VW8 do { asm volatile("s_waitcnt vmcnt(8)" ::: "memory"); __builtin_amdgcn_sched_barrier(0); } while(0)
#define VW4 do { asm volatile("s_waitcnt vmcnt(4)" ::: "memory"); __builtin_amdgcn_sched_barrier(0); } while(0)
#define VW0 do { asm volatile("s_waitcnt vmcnt(0)" ::: "memory"); __builtin_amdgcn_sched_barrier(0); } while(0)
#define LK0 do { asm volatile("s_waitcnt lgkmcnt(0)" ::: "memory"); __builtin_amdgcn_sched_barrier(0); } while(0)
#define SBAR __builtin_amdgcn_s_barrier()

typedef unsigned char uchar;
typedef short short8 __attribute__((ext_vector_type(8)));
typedef float f32x4 __attribute__((ext_vector_type(4)));

__device__ __forceinline__ ushort f2bf(float f) {
    unsigned u = __float_as_uint(f);
    return (ushort)((u + 0x7FFFu + ((u >> 16) & 1u)) >> 16);   // RNE
}
__device__ __forceinline__ float bf2f(ushort h) {
    return __uint_as_float(((unsigned)h) << 16);
}
__device__ __forceinline__ void gload_lds16(const void* g, void* l) {
    __builtin_amdgcn_global_load_lds(
        (const __attribute__((address_space(1))) void*)g,
        (__attribute__((address_space(3))) void*)l, 16, 0, 0);
}

// ---------------------------------------------------------------------------
// R12 = R11 geometry (A-halo per kh, M=64px, grid 1024 XCD-swizzled) with
// T3/T4 sync: B triple-buffered, raw s_barrier, counted vmcnt(4) so B-loads
// stay in flight across barriers (never drain to 0 in steady state).
// Per step q: compute(buf q%3); vmcnt(4); s_barrier; issue B(q+3)->buf q%3.
// kh-boundary restages are full drains (in-order vmcnt makes that forced).
// T5: s_setprio(1) around MFMA cluster.
// ---------------------------------------------------------------------------

__global__ __launch_bounds__(256) void mask_kernel(const int* __restrict__ mask,
                                                   uchar* __restrict__ m1,
                                                   int* __restrict__ cnt)
{
    int idx = blockIdx.x * 256 + threadIdx.x;   // 65536
    int ow = idx & 127;
    int oh = (idx >> 7) & 127;
    int b  = idx >> 14;
    bool act = false;
    #pragma unroll
    for (int kh = 0; kh < 3; ++kh) {
        int ih = 2*oh - 1 + kh;
        if ((unsigned)ih >= 256u) continue;
        #pragma unroll
        for (int kw = 0; kw < 3; ++kw) {
            int iw = 2*ow - 1 + kw;
            if ((unsigned)iw >= 256u) continue;
            if (mask[(b*256 + ih)*256 + iw] == 0) act = true;
        }
    }
    m1[idx] = act ? 1 : 0;
    unsigned long long bal = __ballot(act);
    if ((threadIdx.x & 63) == 0)
        atomicAdd(cnt, (int)__popcll(bal));
}

__global__ __launch_bounds__(256) void wcvt_kernel(const float* __restrict__ w1,
                                                   const float* __restrict__ w2,
                                                   ushort* __restrict__ w1T,
                                                   ushort* __restrict__ w2T)
{
    int idx = blockIdx.x * 256 + threadIdx.x;   // 221184 total
    if (idx < 73728) {                          // 9*128*64
        int ci = idx & 63;
        int co = (idx >> 6) & 127;
        int s  = idx >> 13;
        w1T[idx] = f2bf(w1[(s*64 + ci)*128 + co]);
    } else if (idx < 221184) {
        int i  = idx - 73728;                   // 9*128*128
        int ci = i & 127;
        int co = (i >> 7) & 127;
        int s  = i >> 14;
        w2T[i] = f2bf(w2[(s*128 + ci)*128 + co]);
    }
}

// conv1: 3x3 s2, 64->128, x f32 + mask fused into halo staging.
__global__ __launch_bounds__(256) void conv1_mfma(const float* __restrict__ x,
                                                  const int* __restrict__ mask,
                                                  const ushort* __restrict__ w1T,
                                                  const uchar* __restrict__ m1,
                                                  ushort* __restrict__ out1,
                                                  float* __restrict__ stats)
{
    __shared__ ushort Ah[132 * 64];     // 16,896 B, swizzled ^(((c>>1)&7)<<4)
    __shared__ ushort Bd[3][8192];      // 3 x 16 KB

    const int t     = threadIdx.x;
    const int lane  = t & 63;
    const int wv    = t >> 6;
    const int wbase = t & ~63;
    const int bid   = blockIdx.x;
    const int L     = (bid & 7) * 128 + (bid >> 3);   // XCD-chunked, bijective
    const int half  = L & 1;
    const int oh    = (L >> 1) & 127;
    const int b     = L >> 8;
    const int ow0   = half * 64;
    const int iw0   = 2*ow0 - 1;

    const int wm = wv >> 1, wn = wv & 1;     // wave: 32px x 64co
    const int lr = lane & 15, lg = lane >> 4;

    auto stageA = [&](int kh) {
        int ih  = 2*oh + kh - 1;
        bool rok = ((unsigned)ih < 256u);
        int ihc = ih < 0 ? 0 : (ih > 255 ? 255 : ih);
        const float* xr = x + (size_t)(b*256 + ihc) * 256 * 64;
        const int*   mr = mask + (size_t)(b*256 + ihc) * 256;
        for (int idx = t; idx < 1056; idx += 256) {   // 132 cols x 8 chunks
            int c = idx >> 3, k = idx & 7;
            int iw = iw0 + c;
            short8 v = {0,0,0,0,0,0,0,0};
            if (rok && (unsigned)iw < 256u && mr[iw] == 0) {
                const float* p = xr + (size_t)iw*64 + k*8;
                float4 fa = *(const float4*)p;
                float4 fb = *(const float4*)(p + 4);
                v[0]=(short)f2bf(fa.x); v[1]=(short)f2bf(fa.y);
                v[2]=(short)f2bf(fa.z); v[3]=(short)f2bf(fa.w);
                v[4]=(short)f2bf(fb.x); v[5]=(short)f2bf(fb.y);
                v[6]=(short)f2bf(fb.z); v[7]=(short)f2bf(fb.w);
            }
            int ad = (c*128 + k*16) ^ ((((unsigned)c >> 1) & 7) << 4);
            *(short8*)((char*)Ah + ad) = v;
        }
    };
    const int coB = t >> 3;                  // co = r*32 + coB
    const int dB  = t & 7;
    auto dmaB = [&](int buf, int tap) {
        #pragma unroll
        for (int r = 0; r < 4; ++r) {
            int co = r*32 + coB;
            const ushort* g = w1T + (size_t)tap*8192 + (size_t)co*64
                            + ((dB ^ (co & 7)) << 3);
            gload_lds16(g, &Bd[buf][(size_t)(r*256 + wbase)*8]);
        }
    };

    f32x4 acc[2][4];
    #pragma unroll
    for (int mi = 0; mi < 2; ++mi)
        #pragma unroll
        for (int ni = 0; ni < 4; ++ni)
            acc[mi][ni] = (f32x4){0.f, 0.f, 0.f, 0.f};

    // prologue: stageA first (oldest vmem), then B0..B2; B0 ready via VW8.
    stageA(0);
    dmaB(0, 0); dmaB(1, 1); dmaB(2, 2);
    VW8; LK0;
    SBAR;

    #pragma unroll
    for (int q = 0; q < 9; ++q) {
        const int kw = q % 3, cur = q % 3;
        const char* Ab = (const char*)Ah;
        const char* Bb = (const char*)Bd[cur];
        __builtin_amdgcn_s_setprio(1);
        #pragma unroll
        for (int ks = 0; ks < 2; ++ks) {
            short8 af[2], bfr[4];
            #pragma unroll
            for (int mi = 0; mi < 2; ++mi) {
                int c = 2*(wm*32 + mi*16 + lr) + kw;
                af[mi] = *(const short8*)(Ab +
                    ((c*128 + ks*64 + lg*16) ^ ((((unsigned)c >> 1) & 7) << 4)));
            }
            #pragma unroll
            for (int ni = 0; ni < 4; ++ni) {
                int co = wn*64 + ni*16 + lr;
                bfr[ni] = *(const short8*)(Bb +
                    ((co*128 + ks*64 + lg*16) ^ ((co & 7) << 4)));
            }
            #pragma unroll
            for (int mi = 0; mi < 2; ++mi)
                #pragma unroll
                for (int ni = 0; ni < 4; ++ni)
                    acc[mi][ni] = MFMA16(af[mi], bfr[ni], acc[mi][ni], 0, 0, 0);
        }
        __builtin_amdgcn_s_setprio(0);
        if (q < 8) {
            if (q < 7) VW4; else VW0;        // B(q+1) landed; B(q+2) in flight
            SBAR;
            if (q <= 5) dmaB(q % 3, q + 3);  // into just-freed buffer
            if (kw == 2) {                   // new kh: restage halo (full drain)
                stageA(q/3 + 1);
                LK0;
                SBAR;
            }
        }
    }
    __syncthreads();                         // Ah free for epilogue reuse

    const size_t pixbase = (size_t)(b*128 + oh) * 128 + ow0;
    #pragma unroll
    for (int mi = 0; mi < 2; ++mi) {
        #pragma unroll
        for (int ni = 0; ni < 4; ++ni) {
            int px = wm*32 + mi*16 + lg*4;
            int co = wn*64 + ni*16 + lr;
            #pragma unroll
            for (int r = 0; r < 4; ++r)
                out1[(pixbase + px + r)*128 + co] = f2bf(acc[mi][ni][r]);
        }
    }

    // ---- fused BN1 stats ----
    float s4[4] = {0.f,0.f,0.f,0.f}, q4[4] = {0.f,0.f,0.f,0.f};
    #pragma unroll
    for (int mi = 0; mi < 2; ++mi) {
        const uchar* mp = m1 + pixbase + wm*32 + mi*16 + lg*4;
        #pragma unroll
        for (int r = 0; r < 4; ++r) {
            float a = mp[r] ? 1.f : 0.f;
            #pragma unroll
            for (int ni = 0; ni < 4; ++ni) {
                float av = a * acc[mi][ni][r];
                s4[ni] += av;
                q4[ni] += av * acc[mi][ni][r];
            }
        }
    }
    float* red = (float*)Ah;
    const int rrow = wm*4 + lg;
    #pragma unroll
    for (int ni = 0; ni < 4; ++ni) {
        red[rrow*128 + wn*64 + ni*16 + lr]        = s4[ni];
        red[1024 + rrow*128 + wn*64 + ni*16 + lr] = q4[ni];
    }
    __syncthreads();
    if (t < 128) {
        float v = 0.f, q = 0.f;
        #pragma unroll
        for (int rr = 0; rr < 8; ++rr) { v += red[rr*128 + t]; q += red[1024 + rr*128 + t]; }
        atomicAdd(&stats[t], v);
        atomicAdd(&stats[128 + t], q);
    }
}

// conv2: 3x3 s1, 128->128 on RAW out1 (BN1+ReLU+m1 fused into halo staging).
__global__ __launch_bounds__(256) void conv2_mfma(const ushort* __restrict__ a,
                                                  const ushort* __restrict__ w2T,
                                                  const uchar* __restrict__ m1,
                                                  const float* __restrict__ sb,
                                                  float* __restrict__ outraw,
                                                  float* __restrict__ stats)
{
    __shared__ ushort Ah[66 * 128];     // 16,896 B, swizzled ^((c&7)<<4)
    __shared__ ushort Bd[3][8192];      // 3 x 16 KB
    __shared__ float scb[256];          // sc[128], bi[128]

    const int t     = threadIdx.x;
    const int lane  = t & 63;
    const int wv    = t >> 6;
    const int wbase = t & ~63;
    const int bid   = blockIdx.x;
    const int L     = (bid & 7) * 128 + (bid >> 3);
    const int half  = L & 1;
    const int oh    = (L >> 1) & 127;
    const int b     = L >> 8;
    const int ow0   = half * 64;

    const int wm = wv >> 1, wn = wv & 1;
    const int lr = lane & 15, lg = lane >> 4;

    scb[t] = sb[t & 255];

    auto stageA = [&](int kh) {
        int ih  = oh + kh - 1;
        bool rok = ((unsigned)ih < 128u);
        int ihc = ih < 0 ? 0 : (ih > 127 ? 127 : ih);
        const ushort* ar = a + (size_t)(b*128 + ihc) * 128 * 128;
        const uchar*  mr = m1 + (size_t)(b*128 + ihc) * 128;
        for (int idx = t; idx < 1056; idx += 256) {   // 66 cols x 16 chunks
            int c = idx >> 4, k = idx & 15;
            int iw = ow0 - 1 + c;
            short8 v = {0,0,0,0,0,0,0,0};
            if (rok && (unsigned)iw < 128u && mr[iw]) {
                short8 rv = *(const short8*)(ar + (size_t)iw*128 + k*8);
                #pragma unroll
                for (int j = 0; j < 8; ++j) {
                    float f = fmaf(bf2f((ushort)rv[j]), scb[k*8 + j], scb[128 + k*8 + j]);
                    v[j] = (short)f2bf(fmaxf(f, 0.f));
                }
            }
            int ad = (c*256 + k*16) ^ ((c & 7) << 4);
            *(short8*)((char*)Ah + ad) = v;
        }
    };
    const int coB = t >> 3;
    const int dB  = t & 7;
    auto dmaB = [&](int buf, int q) {
        const int s = q / 6;
        const int j = q % 6;
        const int tap = s*3 + (j >> 1);
        const int h = j & 1;
        #pragma unroll
        for (int r = 0; r < 4; ++r) {
            int co = r*32 + coB;
            const ushort* g = w2T + (size_t)tap*16384 + (size_t)co*128 + h*64
                            + ((dB ^ (co & 7)) << 3);
            gload_lds16(g, &Bd[buf][(size_t)(r*256 + wbase)*8]);
        }
    };

    f32x4 acc[2][4];
    #pragma unroll
    for (int mi = 0; mi < 2; ++mi)
        #pragma unroll
        for (int ni = 0; ni < 4; ++ni)
            acc[mi][ni] = (f32x4){0.f, 0.f, 0.f, 0.f};

    __syncthreads();                         // scb visible
    stageA(0);
    dmaB(0, 0); dmaB(1, 1); dmaB(2, 2);
    VW8; LK0;
    SBAR;

    #pragma unroll
    for (int q = 0; q < 18; ++q) {
        const int j = q % 6;
        const int kw_ = j >> 1, h = j & 1, cur = q % 3;
        const char* Ab = (const char*)Ah;
        const char* Bb = (const char*)Bd[cur];
        __builtin_amdgcn_s_setprio(1);
        #pragma unroll
        for (int ks = 0; ks < 2; ++ks) {
            short8 af[2], bfr[4];
            #pragma unroll
            for (int mi = 0; mi < 2; ++mi) {
                int c = wm*32 + mi*16 + lr + kw_;
                af[mi] = *(const short8*)(Ab +
                    ((c*256 + h*128 + ks*64 + lg*16) ^ ((c & 7) << 4)));
            }
            #pragma unroll
            for (int ni = 0; ni < 4; ++ni) {
                int co = wn*64 + ni*16 + lr;
                bfr[ni] = *(const short8*)(Bb +
                    ((co*128 + ks*64 + lg*16) ^ ((co & 7) << 4)));
            }
            #pragma unroll
            for (int mi = 0; mi < 2; ++mi)
                #pragma unroll
                for (int ni = 0; ni < 4; ++ni)
                    acc[mi][ni] = MFMA16(af[mi], bfr[ni], acc[mi][ni], 0, 0, 0);
        }
        __builtin_amdgcn_s_setprio(0);
        if (q < 17) {
            if (q < 16) VW4; else VW0;       // B(q+1) landed; B(q+2) in flight
            SBAR;
            if (q <= 14) dmaB(q % 3, q + 3);
            if (j == 5) {                    // new kh: restage halo (full drain)
                stageA(q/6 + 1);
                LK0;
                SBAR;
            }
        }
    }
    __syncthreads();

    const size_t pixbase = (size_t)(b*128 + oh) * 128 + ow0;
    #pragma unroll
    for (int mi = 0; mi < 2; ++mi) {
        #pragma unroll
        for (int ni = 0; ni < 4; ++ni) {
            int px = wm*32 + mi*16 + lg*4;
            int co = wn*64 + ni*16 + lr;
            #pragma unroll
            for (int r = 0; r < 4; ++r)
                outraw[(pixbase + px + r)*128 + co] = acc[mi][ni][r];
        }
    }

    // ---- fused BN2 stats ----
    float s4[4] = {0.f,0.f,0.f,0.f}, q4[4] = {0.f,0.f,0.f,0.f};
    #pragma unroll
    for (int mi = 0; mi < 2; ++mi) {
        const uchar* mp = m1 + pixbase + wm*32 + mi*16 + lg*4;
        #pragma unroll
        for (int r = 0; r < 4; ++r) {
            float av0 = mp[r] ? 1.f : 0.f;
            #pragma unroll
            for (int ni = 0; ni < 4; ++ni) {
                float av = av0 * acc[mi][ni][r];
                s4[ni] += av;
                q4[ni] += av * acc[mi][ni][r];
            }
        }
    }
    float* red = (float*)Ah;
    const int rrow = wm*4 + lg;
    #pragma unroll
    for (int ni = 0; ni < 4; ++ni) {
        red[rrow*128 + wn*64 + ni*16 + lr]        = s4[ni];
        red[1024 + rrow*128 + wn*64 + ni*16 + lr] = q4[ni];
    }
    __syncthreads();
    if (t < 128) {
        float v = 0.f, q = 0.f;
        #pragma unroll
        for (int rr = 0; rr < 8; ++rr) { v += red[rr*128 + t]; q += red[1024 + rr*128 + t]; }
        atomicAdd(&stats[t], v);
        atomicAdd(&stats[128 + t], q);
    }
}

__global__ void finalize_kernel(const float* __restrict__ stats,
                                const float* __restrict__ gamma,
                                const float* __restrict__ beta,
                                float* __restrict__ sbout,
                                const int* __restrict__ cnt)
{
    int c = threadIdx.x;   // 128
    float n = (float)(*cnt);
    float mean = stats[c] / n;
    float var  = stats[128 + c] / n - mean*mean;
    var = fmaxf(var, 0.f);
    float scale = gamma[c] * rsqrtf(var + EPS_BN);
    sbout[c]       = scale;
    sbout[128 + c] = beta[c] - mean*scale;
}

// d_out <- m1 ? raw*sc2+bi2 : 0 (f32 in-place)
__global__ __launch_bounds__(256) void apply_kernel(float* __restrict__ out,
                                                    const uchar* __restrict__ m1,
                                                    const float* __restrict__ sb)
{
    int idx4 = blockIdx.x * 256 + threadIdx.x;   // 2,097,152 float4s
    int pos = idx4 >> 5;
    int c4  = (idx4 & 31) << 2;
    float4 v = ((const float4*)out)[idx4];
    float4 r = make_float4(0.f, 0.f, 0.f, 0.f);
    if (m1[pos]) {
        r.x = fmaf(v.x, sb[c4+0], sb[128+c4+0]);
        r.y = fmaf(v.y, sb[c4+1], sb[128+c4+1]);
        r.z = fmaf(v.z, sb[c4+2], sb[128+c4+2]);
        r.w = fmaf(v.w, sb[c4+3], sb[128+c4+3]);
    }
    ((float4*)out)[idx4] = r;
}

extern "C" void kernel_launch(void* const* d_in, const int* in_sizes, int n_in,
                              void* d_out, int out_size, void* d_ws, size_t ws_size,
                              hipStream_t stream)
{
    const float* x      = (const float*)d_in[0];
    const int*   mask   = (const int*)d_in[1];
    const float* w1     = (const float*)d_in[2];
    const float* gamma1 = (const float*)d_in[3];
    const float* beta1  = (const float*)d_in[4];
    const float* w2     = (const float*)d_in[5];
    const float* gamma2 = (const float*)d_in[6];
    const float* beta2  = (const float*)d_in[7];

    ushort* out1 = (ushort*)d_ws;                    // 65536*128 bf16 (raw conv1)
    ushort* w1T  = out1 + 8388608;                   // 9*128*64
    ushort* w2T  = w1T + 73728;                      // 9*128*128
    float* stats = (float*)(w2T + 147456);           // 512 (256 per BN)
    float* sb    = stats + 512;                      // 512 (256 per BN)
    int*   cnt   = (int*)(sb + 512);                 // 4
    uchar* m1    = (uchar*)(cnt + 4);                // 65536

    float* out = (float*)d_out;

    hipMemsetAsync(stats, 0, 1024*sizeof(float) + 4*sizeof(int), stream);

    mask_kernel <<<256,  256, 0, stream>>>(mask, m1, cnt);
    wcvt_kernel <<<864,  256, 0, stream>>>(w1, w2, w1T, w2T);
    conv1_mfma  <<<1024, 256, 0, stream>>>(x, mask, w1T, m1, out1, stats);
    finalize_kernel<<<1, 128, 0, stream>>>(stats, gamma1, beta1, sb, cnt);
    conv2_mfma  <<<1024, 256, 0, stream>>>(out1, w2T, m1, sb, out, stats + 256);
    finalize_kernel<<<1, 128, 0, stream>>>(stats + 256, gamma2, beta2, sb + 256, cnt);
    apply_kernel<<<8192, 256, 0, stream>>>(out, m1, sb + 256);
}

// Round 13
// 112.036 us; speedup vs baseline: 1.2883x; 1.1712x over previous
//
#include <hip/hip_runtime.h>

#define EPS_BN 1e-5f
#define MFMA16 __builtin_amdgcn_mfma_f32_16x16x32_bf16

typedef unsigned char uchar;
typedef short short8 __attribute__((ext_vector_type(8)));
typedef float f32x4 __attribute__((ext_vector_type(4)));

__device__ __forceinline__ ushort f2bf(float f) {
    unsigned u = __float_as_uint(f);
    return (ushort)((u + 0x7FFFu + ((u >> 16) & 1u)) >> 16);   // RNE
}
__device__ __forceinline__ float bf2f(ushort h) {
    return __uint_as_float(((unsigned)h) << 16);
}
__device__ __forceinline__ void gload_lds16(const void* g, void* l) {
    __builtin_amdgcn_global_load_lds(
        (const __attribute__((address_space(1))) void*)g,
        (__attribute__((address_space(3))) void*)l, 16, 0, 0);
}

// ---------------------------------------------------------------------------
// R13: m230-geometry convs. Block = 256px (2 image rows) x 128co, 512 thr /
// 8 waves (wave tile 64px x 64co, acc[4][4]), grid 256 = 1 block/CU, one
// generation. A-halo per kh staged in LDS (reg path, XOR-swizzled both
// sides); B streamed 16KB/step via gload_lds dbuf, issued BEFORE compute
// (R8-proven order), plain __syncthreads 2-phase (m230: 682 TF at this
// geometry). LDS ~100KB.
// MFMA maps (mfma_f32_16x16x32_bf16):
//   A: lane(lr,lg)=lr+16*lg holds A[row=lr][k=lg*8..+8)
//   B: lane holds B[k=lg*8..+8)[col=lr]; weights [co][ci] so co=col
//   D: lane holds D[row=lg*4+r][col=lr], r=0..3
// ---------------------------------------------------------------------------

__global__ __launch_bounds__(256) void mask_kernel(const int* __restrict__ mask,
                                                   uchar* __restrict__ m1,
                                                   int* __restrict__ cnt)
{
    int idx = blockIdx.x * 256 + threadIdx.x;   // 65536
    int ow = idx & 127;
    int oh = (idx >> 7) & 127;
    int b  = idx >> 14;
    bool act = false;
    #pragma unroll
    for (int kh = 0; kh < 3; ++kh) {
        int ih = 2*oh - 1 + kh;
        if ((unsigned)ih >= 256u) continue;
        #pragma unroll
        for (int kw = 0; kw < 3; ++kw) {
            int iw = 2*ow - 1 + kw;
            if ((unsigned)iw >= 256u) continue;
            if (mask[(b*256 + ih)*256 + iw] == 0) act = true;
        }
    }
    m1[idx] = act ? 1 : 0;
    unsigned long long bal = __ballot(act);
    if ((threadIdx.x & 63) == 0)
        atomicAdd(cnt, (int)__popcll(bal));
}

__global__ __launch_bounds__(256) void wcvt_kernel(const float* __restrict__ w1,
                                                   const float* __restrict__ w2,
                                                   ushort* __restrict__ w1T,
                                                   ushort* __restrict__ w2T)
{
    int idx = blockIdx.x * 256 + threadIdx.x;   // 221184 total
    if (idx < 73728) {                          // 9*128*64
        int ci = idx & 63;
        int co = (idx >> 6) & 127;
        int s  = idx >> 13;
        w1T[idx] = f2bf(w1[(s*64 + ci)*128 + co]);
    } else if (idx < 221184) {
        int i  = idx - 73728;                   // 9*128*128
        int ci = i & 127;
        int co = (i >> 7) & 127;
        int s  = i >> 14;
        w2T[i] = f2bf(w2[(s*128 + ci)*128 + co]);
    }
}

// conv1: 3x3 s2, 64->128. Block = output rows {2g,2g+1} x 128co = 256px.
// A-halo per kh: Ah[2][258][64] bf16 (66,048B), swizzle ^(((c>>1)&7)<<4).
// B per tap 16KB, dbuf. 9 steps.
__global__ __launch_bounds__(512) void conv1_mfma(const float* __restrict__ x,
                                                  const int* __restrict__ mask,
                                                  const ushort* __restrict__ w1T,
                                                  const uchar* __restrict__ m1,
                                                  ushort* __restrict__ out1,
                                                  float* __restrict__ stats)
{
    __shared__ ushort Ah[2 * 258 * 64];   // 66,048 B
    __shared__ ushort Bd[2][8192];        // 2 x 16 KB

    const int t     = threadIdx.x;
    const int lane  = t & 63;
    const int wv    = t >> 6;             // 0..7
    const int wbase = t & ~63;
    const int bid   = blockIdx.x;
    const int L     = (bid & 7) * 32 + (bid >> 3);   // XCD-chunked, 256%8==0
    const int g     = L & 63;
    const int b     = L >> 6;

    const int wm = wv >> 1, wn = wv & 1;  // wave: 64px x 64co
    const int lr = lane & 15, lg = lane >> 4;

    auto stageA = [&](int kh) {
        for (int idx = t; idx < 4128; idx += 512) {   // 2 rows x 258c x 8k
            int r   = idx >= 2064;
            int rem = idx - r*2064;
            int c = rem >> 3, k = rem & 7;
            int iw = c - 1;
            int ih = 4*g + 2*r + kh - 1;
            short8 v = {0,0,0,0,0,0,0,0};
            if ((unsigned)ih < 256u && (unsigned)iw < 256u) {
                const int* mr = mask + (size_t)(b*256 + ih) * 256;
                if (mr[iw] == 0) {
                    const float* p = x + ((size_t)(b*256 + ih)*256 + iw)*64 + k*8;
                    float4 fa = *(const float4*)p;
                    float4 fb = *(const float4*)(p + 4);
                    v[0]=(short)f2bf(fa.x); v[1]=(short)f2bf(fa.y);
                    v[2]=(short)f2bf(fa.z); v[3]=(short)f2bf(fa.w);
                    v[4]=(short)f2bf(fb.x); v[5]=(short)f2bf(fb.y);
                    v[6]=(short)f2bf(fb.z); v[7]=(short)f2bf(fb.w);
                }
            }
            int ad = ((r*258 + c)*128 + k*16) ^ ((((unsigned)c >> 1) & 7) << 4);
            *(short8*)((char*)Ah + ad) = v;
        }
    };
    const int coB = t >> 3;               // + r*64
    const int kB  = t & 7;
    auto dmaB = [&](int buf, int tap) {
        #pragma unroll
        for (int r = 0; r < 2; ++r) {
            int co = r*64 + coB;
            const ushort* gp = w1T + (size_t)tap*8192 + (size_t)co*64
                             + ((kB ^ (co & 7)) << 3);
            gload_lds16(gp, &Bd[buf][(size_t)(r*512 + wbase)*8]);
        }
    };

    f32x4 acc[4][4];
    #pragma unroll
    for (int mi = 0; mi < 4; ++mi)
        #pragma unroll
        for (int ni = 0; ni < 4; ++ni)
            acc[mi][ni] = (f32x4){0.f, 0.f, 0.f, 0.f};

    stageA(0);
    dmaB(0, 0);
    __syncthreads();

    for (int kt = 0; kt < 9; ++kt) {
        const int kw = kt % 3, cb = kt & 1;
        if (kt < 8) dmaB(cb ^ 1, kt + 1);          // issue BEFORE compute
        const char* Ab = (const char*)Ah;
        const char* Bb = (const char*)Bd[cb];
        __builtin_amdgcn_s_setprio(1);
        #pragma unroll
        for (int ks = 0; ks < 2; ++ks) {
            short8 af[4], bfr[4];
            #pragma unroll
            for (int mi = 0; mi < 4; ++mi) {
                int px = wm*64 + mi*16 + lr;
                int r  = px >> 7, ow = px & 127;
                int c  = 2*ow + kw;
                af[mi] = *(const short8*)(Ab +
                    (((r*258 + c)*128 + ks*64 + lg*16) ^ ((((unsigned)c >> 1) & 7) << 4)));
            }
            #pragma unroll
            for (int ni = 0; ni < 4; ++ni) {
                int co = wn*64 + ni*16 + lr;
                bfr[ni] = *(const short8*)(Bb +
                    ((co*128 + ks*64 + lg*16) ^ ((co & 7) << 4)));
            }
            #pragma unroll
            for (int mi = 0; mi < 4; ++mi)
                #pragma unroll
                for (int ni = 0; ni < 4; ++ni)
                    acc[mi][ni] = MFMA16(af[mi], bfr[ni], acc[mi][ni], 0, 0, 0);
        }
        __builtin_amdgcn_s_setprio(0);
        __syncthreads();
        if (kw == 2 && kt < 8) {                    // kh boundary: restage halo
            stageA(kt/3 + 1);
            __syncthreads();
        }
    }

    const size_t pixbase = (size_t)(b*128 + 2*g) * 128;   // pixels
    #pragma unroll
    for (int mi = 0; mi < 4; ++mi) {
        #pragma unroll
        for (int ni = 0; ni < 4; ++ni) {
            int p  = wm*64 + mi*16 + lg*4;
            int co = wn*64 + ni*16 + lr;
            #pragma unroll
            for (int r = 0; r < 4; ++r)
                out1[(pixbase + p + r)*128 + co] = f2bf(acc[mi][ni][r]);
        }
    }

    // ---- fused BN1 stats ----
    float s4[4] = {0.f,0.f,0.f,0.f}, q4[4] = {0.f,0.f,0.f,0.f};
    #pragma unroll
    for (int mi = 0; mi < 4; ++mi) {
        const uchar* mp = m1 + pixbase + wm*64 + mi*16 + lg*4;
        #pragma unroll
        for (int r = 0; r < 4; ++r) {
            float a = mp[r] ? 1.f : 0.f;
            #pragma unroll
            for (int ni = 0; ni < 4; ++ni) {
                float av = a * acc[mi][ni][r];
                s4[ni] += av;
                q4[ni] += av * acc[mi][ni][r];
            }
        }
    }
    float* red = (float*)Ah;              // 16 KB of halo buffer, loop done
    const int rrow = wm*4 + lg;           // 0..15
    #pragma unroll
    for (int ni = 0; ni < 4; ++ni) {
        red[rrow*128 + wn*64 + ni*16 + lr]        = s4[ni];
        red[2048 + rrow*128 + wn*64 + ni*16 + lr] = q4[ni];
    }
    __syncthreads();
    if (t < 128) {
        float v = 0.f, q = 0.f;
        #pragma unroll
        for (int rr = 0; rr < 16; ++rr) { v += red[rr*128 + t]; q += red[2048 + rr*128 + t]; }
        atomicAdd(&stats[t], v);
        atomicAdd(&stats[128 + t], q);
    }
}

// conv2: 3x3 s1, 128->128 on RAW out1 (BN1+ReLU+m1 fused into halo staging).
// Block = output rows {2g,2g+1} x 128co. Ah[2][130][128] bf16 (66,560B),
// swizzle ^((c&7)<<4). B per (tap,ci-half) 16KB, dbuf. 18 steps.
__global__ __launch_bounds__(512) void conv2_mfma(const ushort* __restrict__ a,
                                                  const ushort* __restrict__ w2T,
                                                  const uchar* __restrict__ m1,
                                                  const float* __restrict__ sb,
                                                  float* __restrict__ outraw,
                                                  float* __restrict__ stats)
{
    __shared__ ushort Ah[2 * 130 * 128];  // 66,560 B
    __shared__ ushort Bd[2][8192];        // 2 x 16 KB
    __shared__ float scb[256];

    const int t     = threadIdx.x;
    const int lane  = t & 63;
    const int wv    = t >> 6;
    const int wbase = t & ~63;
    const int bid   = blockIdx.x;
    const int L     = (bid & 7) * 32 + (bid >> 3);
    const int g     = L & 63;
    const int b     = L >> 6;

    const int wm = wv >> 1, wn = wv & 1;
    const int lr = lane & 15, lg = lane >> 4;

    if (t < 256) scb[t] = sb[t];

    auto stageA = [&](int kh) {
        for (int idx = t; idx < 4160; idx += 512) {   // 2 rows x 130c x 16k
            int r   = idx >= 2080;
            int rem = idx - r*2080;
            int c = rem >> 4, k = rem & 15;
            int iw = c - 1;
            int ih = 2*g + r + kh - 1;
            short8 v = {0,0,0,0,0,0,0,0};
            if ((unsigned)ih < 128u && (unsigned)iw < 128u) {
                const uchar* mr = m1 + (size_t)(b*128 + ih) * 128;
                if (mr[iw]) {
                    short8 rv = *(const short8*)(a + ((size_t)(b*128 + ih)*128 + iw)*128 + k*8);
                    #pragma unroll
                    for (int j = 0; j < 8; ++j) {
                        float f = fmaf(bf2f((ushort)rv[j]), scb[k*8 + j], scb[128 + k*8 + j]);
                        v[j] = (short)f2bf(fmaxf(f, 0.f));
                    }
                }
            }
            int ad = ((r*130 + c)*256 + k*16) ^ ((c & 7) << 4);
            *(short8*)((char*)Ah + ad) = v;
        }
    };
    const int coB = t >> 3;
    const int kB  = t & 7;
    auto dmaB = [&](int buf, int kt) {
        const int s = kt / 6, j = kt % 6;
        const int tap = s*3 + (j >> 1);
        const int h = j & 1;
        #pragma unroll
        for (int r = 0; r < 2; ++r) {
            int co = r*64 + coB;
            const ushort* gp = w2T + (size_t)tap*16384 + (size_t)co*128 + h*64
                             + ((kB ^ (co & 7)) << 3);
            gload_lds16(gp, &Bd[buf][(size_t)(r*512 + wbase)*8]);
        }
    };

    f32x4 acc[4][4];
    #pragma unroll
    for (int mi = 0; mi < 4; ++mi)
        #pragma unroll
        for (int ni = 0; ni < 4; ++ni)
            acc[mi][ni] = (f32x4){0.f, 0.f, 0.f, 0.f};

    __syncthreads();                       // scb visible
    stageA(0);
    dmaB(0, 0);
    __syncthreads();

    for (int kt = 0; kt < 18; ++kt) {
        const int j = kt % 6;
        const int kw = j >> 1, h = j & 1, cb = kt & 1;
        if (kt < 17) dmaB(cb ^ 1, kt + 1);          // issue BEFORE compute
        const char* Ab = (const char*)Ah;
        const char* Bb = (const char*)Bd[cb];
        __builtin_amdgcn_s_setprio(1);
        #pragma unroll
        for (int ks = 0; ks < 2; ++ks) {
            short8 af[4], bfr[4];
            #pragma unroll
            for (int mi = 0; mi < 4; ++mi) {
                int px = wm*64 + mi*16 + lr;
                int r  = px >> 7, ow = px & 127;
                int c  = ow + kw;
                af[mi] = *(const short8*)(Ab +
                    (((r*130 + c)*256 + h*128 + ks*64 + lg*16) ^ ((c & 7) << 4)));
            }
            #pragma unroll
            for (int ni = 0; ni < 4; ++ni) {
                int co = wn*64 + ni*16 + lr;
                bfr[ni] = *(const short8*)(Bb +
                    ((co*128 + ks*64 + lg*16) ^ ((co & 7) << 4)));
            }
            #pragma unroll
            for (int mi = 0; mi < 4; ++mi)
                #pragma unroll
                for (int ni = 0; ni < 4; ++ni)
                    acc[mi][ni] = MFMA16(af[mi], bfr[ni], acc[mi][ni], 0, 0, 0);
        }
        __builtin_amdgcn_s_setprio(0);
        __syncthreads();
        if (j == 5 && kt < 17) {                    // kh boundary: restage halo
            stageA(kt/6 + 1);
            __syncthreads();
        }
    }

    const size_t pixbase = (size_t)(b*128 + 2*g) * 128;
    #pragma unroll
    for (int mi = 0; mi < 4; ++mi) {
        #pragma unroll
        for (int ni = 0; ni < 4; ++ni) {
            int p  = wm*64 + mi*16 + lg*4;
            int co = wn*64 + ni*16 + lr;
            #pragma unroll
            for (int r = 0; r < 4; ++r)
                outraw[(pixbase + p + r)*128 + co] = acc[mi][ni][r];
        }
    }

    // ---- fused BN2 stats ----
    float s4[4] = {0.f,0.f,0.f,0.f}, q4[4] = {0.f,0.f,0.f,0.f};
    #pragma unroll
    for (int mi = 0; mi < 4; ++mi) {
        const uchar* mp = m1 + pixbase + wm*64 + mi*16 + lg*4;
        #pragma unroll
        for (int r = 0; r < 4; ++r) {
            float a0 = mp[r] ? 1.f : 0.f;
            #pragma unroll
            for (int ni = 0; ni < 4; ++ni) {
                float av = a0 * acc[mi][ni][r];
                s4[ni] += av;
                q4[ni] += av * acc[mi][ni][r];
            }
        }
    }
    float* red = (float*)Ah;
    const int rrow = wm*4 + lg;
    #pragma unroll
    for (int ni = 0; ni < 4; ++ni) {
        red[rrow*128 + wn*64 + ni*16 + lr]        = s4[ni];
        red[2048 + rrow*128 + wn*64 + ni*16 + lr] = q4[ni];
    }
    __syncthreads();
    if (t < 128) {
        float v = 0.f, q = 0.f;
        #pragma unroll
        for (int rr = 0; rr < 16; ++rr) { v += red[rr*128 + t]; q += red[2048 + rr*128 + t]; }
        atomicAdd(&stats[t], v);
        atomicAdd(&stats[128 + t], q);
    }
}

__global__ void finalize_kernel(const float* __restrict__ stats,
                                const float* __restrict__ gamma,
                                const float* __restrict__ beta,
                                float* __restrict__ sbout,
                                const int* __restrict__ cnt)
{
    int c = threadIdx.x;   // 128
    float n = (float)(*cnt);
    float mean = stats[c] / n;
    float var  = stats[128 + c] / n - mean*mean;
    var = fmaxf(var, 0.f);
    float scale = gamma[c] * rsqrtf(var + EPS_BN);
    sbout[c]       = scale;
    sbout[128 + c] = beta[c] - mean*scale;
}

// d_out <- m1 ? raw*sc2+bi2 : 0 (f32 in-place)
__global__ __launch_bounds__(256) void apply_kernel(float* __restrict__ out,
                                                    const uchar* __restrict__ m1,
                                                    const float* __restrict__ sb)
{
    int idx4 = blockIdx.x * 256 + threadIdx.x;   // 2,097,152 float4s
    int pos = idx4 >> 5;
    int c4  = (idx4 & 31) << 2;
    float4 v = ((const float4*)out)[idx4];
    float4 r = make_float4(0.f, 0.f, 0.f, 0.f);
    if (m1[pos]) {
        r.x = fmaf(v.x, sb[c4+0], sb[128+c4+0]);
        r.y = fmaf(v.y, sb[c4+1], sb[128+c4+1]);
        r.z = fmaf(v.z, sb[c4+2], sb[128+c4+2]);
        r.w = fmaf(v.w, sb[c4+3], sb[128+c4+3]);
    }
    ((float4*)out)[idx4] = r;
}

extern "C" void kernel_launch(void* const* d_in, const int* in_sizes, int n_in,
                              void* d_out, int out_size, void* d_ws, size_t ws_size,
                              hipStream_t stream)
{
    const float* x      = (const float*)d_in[0];
    const int*   mask   = (const int*)d_in[1];
    const float* w1     = (const float*)d_in[2];
    const float* gamma1 = (const float*)d_in[3];
    const float* beta1  = (const float*)d_in[4];
    const float* w2     = (const float*)d_in[5];
    const float* gamma2 = (const float*)d_in[6];
    const float* beta2  = (const float*)d_in[7];

    ushort* out1 = (ushort*)d_ws;                    // 65536*128 bf16 (raw conv1)
    ushort* w1T  = out1 + 8388608;                   // 9*128*64
    ushort* w2T  = w1T + 73728;                      // 9*128*128
    float* stats = (float*)(w2T + 147456);           // 512 (256 per BN)
    float* sb    = stats + 512;                      // 512 (256 per BN)
    int*   cnt   = (int*)(sb + 512);                 // 4
    uchar* m1    = (uchar*)(cnt + 4);                // 65536

    float* out = (float*)d_out;

    hipMemsetAsync(stats, 0, 1024*sizeof(float) + 4*sizeof(int), stream);

    mask_kernel <<<256, 256, 0, stream>>>(mask, m1, cnt);
    wcvt_kernel <<<864, 256, 0, stream>>>(w1, w2, w1T, w2T);
    conv1_mfma  <<<256, 512, 0, stream>>>(x, mask, w1T, m1, out1, stats);
    finalize_kernel<<<1, 128, 0, stream>>>(stats, gamma1, beta1, sb, cnt);
    conv2_mfma  <<<256, 512, 0, stream>>>(out1, w2T, m1, sb, out, stats + 256);
    finalize_kernel<<<1, 128, 0, stream>>>(stats + 256, gamma2, beta2, sb + 256, cnt);
    apply_kernel<<<8192, 256, 0, stream>>>(out, m1, sb + 256);
}

// Round 14
// 105.117 us; speedup vs baseline: 1.3731x; 1.0658x over previous
//
#include <hip/hip_runtime.h>
#include <hip/hip_bf16.h>

#define EPS_BN 1e-5f
#define MFMA16 __builtin_amdgcn_mfma_f32_16x16x32_bf16

typedef unsigned char uchar;
typedef short short8 __attribute__((ext_vector_type(8)));
typedef float f32x4 __attribute__((ext_vector_type(4)));

__device__ __forceinline__ ushort f2bf(float f) {
    __hip_bfloat16 h = __float2bfloat16(f);     // RNE; compiler can pack pairs
    return *(ushort*)&h;
}
__device__ __forceinline__ float bf2f(ushort h) {
    return __uint_as_float(((unsigned)h) << 16);
}
__device__ __forceinline__ void gload_lds16(const void* g, void* l) {
    __builtin_amdgcn_global_load_lds(
        (const __attribute__((address_space(1))) void*)g,
        (__attribute__((address_space(3))) void*)l, 16, 0, 0);
}

// ---------------------------------------------------------------------------
// R14 = R13 geometry (256px x 128co block, 8 waves, 1 block/CU) with
// conv2 BK=128 (full Cin per tap): 9 K-steps instead of 18 -> barrier-units
// 20 -> 11. B-tile 32KB/tap dbuf (64KB); LDS 133KB. #pragma unroll on main
// loops; native __float2bfloat16 in staging (packed cvt).
// MFMA maps (mfma_f32_16x16x32_bf16):
//   A: lane(lr,lg)=lr+16*lg holds A[row=lr][k=lg*8..+8)
//   B: lane holds B[k=lg*8..+8)[col=lr]; weights [co][ci] so co=col
//   D: lane holds D[row=lg*4+r][col=lr], r=0..3
// ---------------------------------------------------------------------------

__global__ __launch_bounds__(256) void mask_kernel(const int* __restrict__ mask,
                                                   uchar* __restrict__ m1,
                                                   int* __restrict__ cnt)
{
    int idx = blockIdx.x * 256 + threadIdx.x;   // 65536
    int ow = idx & 127;
    int oh = (idx >> 7) & 127;
    int b  = idx >> 14;
    bool act = false;
    #pragma unroll
    for (int kh = 0; kh < 3; ++kh) {
        int ih = 2*oh - 1 + kh;
        if ((unsigned)ih >= 256u) continue;
        #pragma unroll
        for (int kw = 0; kw < 3; ++kw) {
            int iw = 2*ow - 1 + kw;
            if ((unsigned)iw >= 256u) continue;
            if (mask[(b*256 + ih)*256 + iw] == 0) act = true;
        }
    }
    m1[idx] = act ? 1 : 0;
    unsigned long long bal = __ballot(act);
    if ((threadIdx.x & 63) == 0)
        atomicAdd(cnt, (int)__popcll(bal));
}

__global__ __launch_bounds__(256) void wcvt_kernel(const float* __restrict__ w1,
                                                   const float* __restrict__ w2,
                                                   ushort* __restrict__ w1T,
                                                   ushort* __restrict__ w2T)
{
    int idx = blockIdx.x * 256 + threadIdx.x;   // 221184 total
    if (idx < 73728) {                          // 9*128*64
        int ci = idx & 63;
        int co = (idx >> 6) & 127;
        int s  = idx >> 13;
        w1T[idx] = f2bf(w1[(s*64 + ci)*128 + co]);
    } else if (idx < 221184) {
        int i  = idx - 73728;                   // 9*128*128
        int ci = i & 127;
        int co = (i >> 7) & 127;
        int s  = i >> 14;
        w2T[i] = f2bf(w2[(s*128 + ci)*128 + co]);
    }
}

// conv1: 3x3 s2, 64->128. Block = output rows {2g,2g+1} x 128co = 256px.
__global__ __launch_bounds__(512) void conv1_mfma(const float* __restrict__ x,
                                                  const int* __restrict__ mask,
                                                  const ushort* __restrict__ w1T,
                                                  const uchar* __restrict__ m1,
                                                  ushort* __restrict__ out1,
                                                  float* __restrict__ stats)
{
    __shared__ ushort Ah[2 * 258 * 64];   // 66,048 B
    __shared__ ushort Bd[2][8192];        // 2 x 16 KB

    const int t     = threadIdx.x;
    const int lane  = t & 63;
    const int wv    = t >> 6;             // 0..7
    const int wbase = t & ~63;
    const int bid   = blockIdx.x;
    const int L     = (bid & 7) * 32 + (bid >> 3);   // XCD-chunked, 256%8==0
    const int g     = L & 63;
    const int b     = L >> 6;

    const int wm = wv >> 1, wn = wv & 1;  // wave: 64px x 64co
    const int lr = lane & 15, lg = lane >> 4;

    auto stageA = [&](int kh) {
        for (int idx = t; idx < 4128; idx += 512) {   // 2 rows x 258c x 8k
            int r   = idx >= 2064;
            int rem = idx - r*2064;
            int c = rem >> 3, k = rem & 7;
            int iw = c - 1;
            int ih = 4*g + 2*r + kh - 1;
            short8 v = {0,0,0,0,0,0,0,0};
            if ((unsigned)ih < 256u && (unsigned)iw < 256u) {
                const int* mr = mask + (size_t)(b*256 + ih) * 256;
                if (mr[iw] == 0) {
                    const float* p = x + ((size_t)(b*256 + ih)*256 + iw)*64 + k*8;
                    float4 fa = *(const float4*)p;
                    float4 fb = *(const float4*)(p + 4);
                    v[0]=(short)f2bf(fa.x); v[1]=(short)f2bf(fa.y);
                    v[2]=(short)f2bf(fa.z); v[3]=(short)f2bf(fa.w);
                    v[4]=(short)f2bf(fb.x); v[5]=(short)f2bf(fb.y);
                    v[6]=(short)f2bf(fb.z); v[7]=(short)f2bf(fb.w);
                }
            }
            int ad = ((r*258 + c)*128 + k*16) ^ ((((unsigned)c >> 1) & 7) << 4);
            *(short8*)((char*)Ah + ad) = v;
        }
    };
    const int coB = t >> 3;               // + r*64
    const int kB  = t & 7;
    auto dmaB = [&](int buf, int tap) {
        #pragma unroll
        for (int r = 0; r < 2; ++r) {
            int co = r*64 + coB;
            const ushort* gp = w1T + (size_t)tap*8192 + (size_t)co*64
                             + ((kB ^ (co & 7)) << 3);
            gload_lds16(gp, &Bd[buf][(size_t)(r*512 + wbase)*8]);
        }
    };

    f32x4 acc[4][4];
    #pragma unroll
    for (int mi = 0; mi < 4; ++mi)
        #pragma unroll
        for (int ni = 0; ni < 4; ++ni)
            acc[mi][ni] = (f32x4){0.f, 0.f, 0.f, 0.f};

    stageA(0);
    dmaB(0, 0);
    __syncthreads();

    #pragma unroll
    for (int kt = 0; kt < 9; ++kt) {
        const int kw = kt % 3, cb = kt & 1;
        if (kt < 8) dmaB(cb ^ 1, kt + 1);          // issue BEFORE compute
        const char* Ab = (const char*)Ah;
        const char* Bb = (const char*)Bd[cb];
        __builtin_amdgcn_s_setprio(1);
        #pragma unroll
        for (int ks = 0; ks < 2; ++ks) {
            short8 af[4], bfr[4];
            #pragma unroll
            for (int mi = 0; mi < 4; ++mi) {
                int px = wm*64 + mi*16 + lr;
                int r  = px >> 7, ow = px & 127;
                int c  = 2*ow + kw;
                af[mi] = *(const short8*)(Ab +
                    (((r*258 + c)*128 + ks*64 + lg*16) ^ ((((unsigned)c >> 1) & 7) << 4)));
            }
            #pragma unroll
            for (int ni = 0; ni < 4; ++ni) {
                int co = wn*64 + ni*16 + lr;
                bfr[ni] = *(const short8*)(Bb +
                    ((co*128 + ks*64 + lg*16) ^ ((co & 7) << 4)));
            }
            #pragma unroll
            for (int mi = 0; mi < 4; ++mi)
                #pragma unroll
                for (int ni = 0; ni < 4; ++ni)
                    acc[mi][ni] = MFMA16(af[mi], bfr[ni], acc[mi][ni], 0, 0, 0);
        }
        __builtin_amdgcn_s_setprio(0);
        __syncthreads();
        if (kw == 2 && kt < 8) {                    // kh boundary: restage halo
            stageA(kt/3 + 1);
            __syncthreads();
        }
    }

    const size_t pixbase = (size_t)(b*128 + 2*g) * 128;   // pixels
    #pragma unroll
    for (int mi = 0; mi < 4; ++mi) {
        #pragma unroll
        for (int ni = 0; ni < 4; ++ni) {
            int p  = wm*64 + mi*16 + lg*4;
            int co = wn*64 + ni*16 + lr;
            #pragma unroll
            for (int r = 0; r < 4; ++r)
                out1[(pixbase + p + r)*128 + co] = f2bf(acc[mi][ni][r]);
        }
    }

    // ---- fused BN1 stats ----
    float s4[4] = {0.f,0.f,0.f,0.f}, q4[4] = {0.f,0.f,0.f,0.f};
    #pragma unroll
    for (int mi = 0; mi < 4; ++mi) {
        const uchar* mp = m1 + pixbase + wm*64 + mi*16 + lg*4;
        #pragma unroll
        for (int r = 0; r < 4; ++r) {
            float a = mp[r] ? 1.f : 0.f;
            #pragma unroll
            for (int ni = 0; ni < 4; ++ni) {
                float av = a * acc[mi][ni][r];
                s4[ni] += av;
                q4[ni] += av * acc[mi][ni][r];
            }
        }
    }
    float* red = (float*)Ah;              // halo buffer, loop done
    const int rrow = wm*4 + lg;           // 0..15
    #pragma unroll
    for (int ni = 0; ni < 4; ++ni) {
        red[rrow*128 + wn*64 + ni*16 + lr]        = s4[ni];
        red[2048 + rrow*128 + wn*64 + ni*16 + lr] = q4[ni];
    }
    __syncthreads();
    if (t < 128) {
        float v = 0.f, q = 0.f;
        #pragma unroll
        for (int rr = 0; rr < 16; ++rr) { v += red[rr*128 + t]; q += red[2048 + rr*128 + t]; }
        atomicAdd(&stats[t], v);
        atomicAdd(&stats[128 + t], q);
    }
}

// conv2: 3x3 s1, 128->128 on RAW out1 (BN1+ReLU+m1 fused into halo staging).
// Block = output rows {2g,2g+1} x 128co. BK=128: B per tap 32KB dbuf, 9 steps.
__global__ __launch_bounds__(512) void conv2_mfma(const ushort* __restrict__ a,
                                                  const ushort* __restrict__ w2T,
                                                  const uchar* __restrict__ m1,
                                                  const float* __restrict__ sb,
                                                  float* __restrict__ outraw,
                                                  float* __restrict__ stats)
{
    __shared__ ushort Ah[2 * 130 * 128];  // 66,560 B, swizzle ^((c&7)<<4)
    __shared__ ushort Bd[2][16384];       // 2 x 32 KB (full ci per tap)
    __shared__ float scb[256];

    const int t     = threadIdx.x;
    const int lane  = t & 63;
    const int wv    = t >> 6;
    const int wbase = t & ~63;
    const int bid   = blockIdx.x;
    const int L     = (bid & 7) * 32 + (bid >> 3);
    const int g     = L & 63;
    const int b     = L >> 6;

    const int wm = wv >> 1, wn = wv & 1;
    const int lr = lane & 15, lg = lane >> 4;

    if (t < 256) scb[t] = sb[t];

    auto stageA = [&](int kh) {
        for (int idx = t; idx < 4160; idx += 512) {   // 2 rows x 130c x 16k
            int r   = idx >= 2080;
            int rem = idx - r*2080;
            int c = rem >> 4, k = rem & 15;
            int iw = c - 1;
            int ih = 2*g + r + kh - 1;
            short8 v = {0,0,0,0,0,0,0,0};
            if ((unsigned)ih < 128u && (unsigned)iw < 128u) {
                const uchar* mr = m1 + (size_t)(b*128 + ih) * 128;
                if (mr[iw]) {
                    short8 rv = *(const short8*)(a + ((size_t)(b*128 + ih)*128 + iw)*128 + k*8);
                    #pragma unroll
                    for (int j = 0; j < 8; ++j) {
                        float f = fmaf(bf2f((ushort)rv[j]), scb[k*8 + j], scb[128 + k*8 + j]);
                        v[j] = (short)f2bf(fmaxf(f, 0.f));
                    }
                }
            }
            int ad = ((r*130 + c)*256 + k*16) ^ ((c & 7) << 4);
            *(short8*)((char*)Ah + ad) = v;
        }
    };
    auto dmaB = [&](int buf, int tap) {    // 32 KB: 2048 chunks, 4 per thread
        #pragma unroll
        for (int r = 0; r < 4; ++r) {
            int idx = r*512 + t;
            int co = idx >> 4, k = idx & 15;
            const ushort* gp = w2T + (size_t)tap*16384 + (size_t)co*128
                             + ((k ^ (co & 7)) << 3);
            gload_lds16(gp, &Bd[buf][(size_t)idx*8]);
        }
    };

    f32x4 acc[4][4];
    #pragma unroll
    for (int mi = 0; mi < 4; ++mi)
        #pragma unroll
        for (int ni = 0; ni < 4; ++ni)
            acc[mi][ni] = (f32x4){0.f, 0.f, 0.f, 0.f};

    __syncthreads();                       // scb visible
    stageA(0);
    dmaB(0, 0);
    __syncthreads();

    #pragma unroll
    for (int kt = 0; kt < 9; ++kt) {
        const int kw = kt % 3, cb = kt & 1;
        if (kt < 8) dmaB(cb ^ 1, kt + 1);          // issue BEFORE compute
        const char* Ab = (const char*)Ah;
        const char* Bb = (const char*)Bd[cb];
        __builtin_amdgcn_s_setprio(1);
        #pragma unroll
        for (int ks = 0; ks < 4; ++ks) {           // full 128 ci
            short8 af[4], bfr[4];
            #pragma unroll
            for (int mi = 0; mi < 4; ++mi) {
                int px = wm*64 + mi*16 + lr;
                int r  = px >> 7, ow = px & 127;
                int c  = ow + kw;
                af[mi] = *(const short8*)(Ab +
                    (((r*130 + c)*256 + ks*64 + lg*16) ^ ((c & 7) << 4)));
            }
            #pragma unroll
            for (int ni = 0; ni < 4; ++ni) {
                int co = wn*64 + ni*16 + lr;
                bfr[ni] = *(const short8*)(Bb +
                    ((co*256 + ks*64 + lg*16) ^ ((co & 7) << 4)));
            }
            #pragma unroll
            for (int mi = 0; mi < 4; ++mi)
                #pragma unroll
                for (int ni = 0; ni < 4; ++ni)
                    acc[mi][ni] = MFMA16(af[mi], bfr[ni], acc[mi][ni], 0, 0, 0);
        }
        __builtin_amdgcn_s_setprio(0);
        __syncthreads();
        if (kw == 2 && kt < 8) {                    // kh boundary: restage halo
            stageA(kt/3 + 1);
            __syncthreads();
        }
    }

    const size_t pixbase = (size_t)(b*128 + 2*g) * 128;
    #pragma unroll
    for (int mi = 0; mi < 4; ++mi) {
        #pragma unroll
        for (int ni = 0; ni < 4; ++ni) {
            int p  = wm*64 + mi*16 + lg*4;
            int co = wn*64 + ni*16 + lr;
            #pragma unroll
            for (int r = 0; r < 4; ++r)
                outraw[(pixbase + p + r)*128 + co] = acc[mi][ni][r];
        }
    }

    // ---- fused BN2 stats ----
    float s4[4] = {0.f,0.f,0.f,0.f}, q4[4] = {0.f,0.f,0.f,0.f};
    #pragma unroll
    for (int mi = 0; mi < 4; ++mi) {
        const uchar* mp = m1 + pixbase + wm*64 + mi*16 + lg*4;
        #pragma unroll
        for (int r = 0; r < 4; ++r) {
            float a0 = mp[r] ? 1.f : 0.f;
            #pragma unroll
            for (int ni = 0; ni < 4; ++ni) {
                float av = a0 * acc[mi][ni][r];
                s4[ni] += av;
                q4[ni] += av * acc[mi][ni][r];
            }
        }
    }
    float* red = (float*)Ah;
    const int rrow = wm*4 + lg;
    #pragma unroll
    for (int ni = 0; ni < 4; ++ni) {
        red[rrow*128 + wn*64 + ni*16 + lr]        = s4[ni];
        red[2048 + rrow*128 + wn*64 + ni*16 + lr] = q4[ni];
    }
    __syncthreads();
    if (t < 128) {
        float v = 0.f, q = 0.f;
        #pragma unroll
        for (int rr = 0; rr < 16; ++rr) { v += red[rr*128 + t]; q += red[2048 + rr*128 + t]; }
        atomicAdd(&stats[t], v);
        atomicAdd(&stats[128 + t], q);
    }
}

__global__ void finalize_kernel(const float* __restrict__ stats,
                                const float* __restrict__ gamma,
                                const float* __restrict__ beta,
                                float* __restrict__ sbout,
                                const int* __restrict__ cnt)
{
    int c = threadIdx.x;   // 128
    float n = (float)(*cnt);
    float mean = stats[c] / n;
    float var  = stats[128 + c] / n - mean*mean;
    var = fmaxf(var, 0.f);
    float scale = gamma[c] * rsqrtf(var + EPS_BN);
    sbout[c]       = scale;
    sbout[128 + c] = beta[c] - mean*scale;
}

// d_out <- m1 ? raw*sc2+bi2 : 0 (f32 in-place)
__global__ __launch_bounds__(256) void apply_kernel(float* __restrict__ out,
                                                    const uchar* __restrict__ m1,
                                                    const float* __restrict__ sb)
{
    int idx4 = blockIdx.x * 256 + threadIdx.x;   // 2,097,152 float4s
    int pos = idx4 >> 5;
    int c4  = (idx4 & 31) << 2;
    float4 v = ((const float4*)out)[idx4];
    float4 r = make_float4(0.f, 0.f, 0.f, 0.f);
    if (m1[pos]) {
        r.x = fmaf(v.x, sb[c4+0], sb[128+c4+0]);
        r.y = fmaf(v.y, sb[c4+1], sb[128+c4+1]);
        r.z = fmaf(v.z, sb[c4+2], sb[128+c4+2]);
        r.w = fmaf(v.w, sb[c4+3], sb[128+c4+3]);
    }
    ((float4*)out)[idx4] = r;
}

extern "C" void kernel_launch(void* const* d_in, const int* in_sizes, int n_in,
                              void* d_out, int out_size, void* d_ws, size_t ws_size,
                              hipStream_t stream)
{
    const float* x      = (const float*)d_in[0];
    const int*   mask   = (const int*)d_in[1];
    const float* w1     = (const float*)d_in[2];
    const float* gamma1 = (const float*)d_in[3];
    const float* beta1  = (const float*)d_in[4];
    const float* w2     = (const float*)d_in[5];
    const float* gamma2 = (const float*)d_in[6];
    const float* beta2  = (const float*)d_in[7];

    ushort* out1 = (ushort*)d_ws;                    // 65536*128 bf16 (raw conv1)
    ushort* w1T  = out1 + 8388608;                   // 9*128*64
    ushort* w2T  = w1T + 73728;                      // 9*128*128
    float* stats = (float*)(w2T + 147456);           // 512 (256 per BN)
    float* sb    = stats + 512;                      // 512 (256 per BN)
    int*   cnt   = (int*)(sb + 512);                 // 4
    uchar* m1    = (uchar*)(cnt + 4);                // 65536

    float* out = (float*)d_out;

    hipMemsetAsync(stats, 0, 1024*sizeof(float) + 4*sizeof(int), stream);

    mask_kernel <<<256, 256, 0, stream>>>(mask, m1, cnt);
    wcvt_kernel <<<864, 256, 0, stream>>>(w1, w2, w1T, w2T);
    conv1_mfma  <<<256, 512, 0, stream>>>(x, mask, w1T, m1, out1, stats);
    finalize_kernel<<<1, 128, 0, stream>>>(stats, gamma1, beta1, sb, cnt);
    conv2_mfma  <<<256, 512, 0, stream>>>(out1, w2T, m1, sb, out, stats + 256);
    finalize_kernel<<<1, 128, 0, stream>>>(stats + 256, gamma2, beta2, sb + 256, cnt);
    apply_kernel<<<8192, 256, 0, stream>>>(out, m1, sb + 256);
}